// Round 10
// baseline (808.264 us; speedup 1.0000x reference)
//
#include <hip/hip_runtime.h>
#include <hip/hip_bf16.h>

// ShockPropagationGNN — round 9.
// - k_va: wave-cooperative va/vat precompute (removes k_prep's serial tail).
// - k_layer: aggregate + output-GEMM fused; g-tile lives in LDS (64x520),
//   no global g. h/al double-buffered (gather-vs-write hazard).

#define N_NODES 50000
#define N_EDGES 200000
#define ETOT    (N_EDGES + N_NODES)
#define HID     128
#define LN_EPS  1e-5f
#define NEG     0.2f

typedef __hip_bfloat16 bf16;
typedef __attribute__((ext_vector_type(8))) short v8s;
typedef __attribute__((ext_vector_type(4))) float v4f;
#define MFMA(a, b, c) __builtin_amdgcn_mfma_f32_16x16x32_bf16(a, b, c, 0, 0, 0)

__device__ __forceinline__ float b2f(unsigned short s) {
    return __uint_as_float(((unsigned int)s) << 16);
}
__device__ __forceinline__ unsigned short f2b(float f) {
    __hip_bfloat16 h = __float2bfloat16(f);
    return *reinterpret_cast<unsigned short*>(&h);
}
__device__ __forceinline__ unsigned int pack2(float a, float b) {
    return (unsigned int)f2b(a) | ((unsigned int)f2b(b) << 16);
}
__device__ __forceinline__ float pread(const void* p, size_t i, int isbf) {
    if (isbf) return b2f(((const unsigned short*)p)[i]);
    return ((const float*)p)[i];
}

__global__ void k_fill(float* out, int n, float v) {
    int i = blockIdx.x * blockDim.x + threadIdx.x;
    if (i < n) out[i] = v;
}

// ------------------------------------------------------------ dtype detect
__global__ void k_detect(const unsigned short* __restrict__ xbuf,
                         int* __restrict__ flag) {
    int sane = 0;
    for (int j = threadIdx.x; j < 4096; j += 64) {
        unsigned short v = xbuf[2 * j];
        int e = (v >> 7) & 0xFF;
        if (v == 0 || (e > 96 && e < 160)) sane++;
    }
    for (int off = 32; off > 0; off >>= 1) sane += __shfl_down(sane, off);
    if (threadIdx.x == 0) flag[0] = (sane * 10 >= 4096 * 9) ? 1 : 0;
}

// ------------------------------------------------------------ prep (fused)
struct PrepArgs {
    const void *encw, *encb, *enlg, *enlb, *gatw, *asrc, *adst, *bias,
               *bng, *bnb, *bnm, *bnv, *em1w, *em1b, *emlg, *emlb,
               *em2w, *em2b, *em3w, *em3b;
};
#define PREP_ITEMS (150000 + 8193 + 196608 + 36864 + 8192)
__global__ void k_prep(PrepArgs a, float* __restrict__ pool,
                       unsigned short* __restrict__ gwt,   // gw2t[L][c=128][hk=512]
                       unsigned short* __restrict__ w1t,
                       unsigned short* __restrict__ w2t,
                       float* __restrict__ down, int* __restrict__ deg,
                       int* __restrict__ fill, const int* __restrict__ flag) {
    int i = blockIdx.x * 256 + threadIdx.x;
    int bf = flag[0];
    if (i < 150000) {
        int which = i / 50000, idx = i - which * 50000;
        if (which == 0) down[idx] = 0.f;
        else if (which == 1) deg[idx] = 0;
        else fill[idx] = 0;
        return;
    }
    i -= 150000;
    if (i < 8193) {
        const void* s; int off;
        if      (i < 2304) { s = a.encw; off = 0;    }
        else if (i < 2432) { s = a.encb; off = 2304; }
        else if (i < 2560) { s = a.enlg; off = 2432; }
        else if (i < 2688) { s = a.enlb; off = 2560; }
        else if (i < 4224) { s = a.asrc; off = 2688; }
        else if (i < 5760) { s = a.adst; off = 4224; }
        else if (i < 6144) { s = a.bias; off = 5760; }
        else if (i < 6528) { s = a.bng;  off = 6144; }
        else if (i < 6912) { s = a.bnb;  off = 6528; }
        else if (i < 7296) { s = a.bnm;  off = 6912; }
        else if (i < 7680) { s = a.bnv;  off = 7296; }
        else if (i < 7808) { s = a.em1b; off = 7680; }
        else if (i < 7936) { s = a.emlg; off = 7808; }
        else if (i < 8064) { s = a.emlb; off = 7936; }
        else if (i < 8128) { s = a.em2b; off = 8064; }
        else if (i < 8192) { s = a.em3w; off = 8128; }
        else               { s = a.em3b; off = 8192; }
        pool[i] = pread(s, i - off, bf);
        return;
    }
    i -= 8193;
    if (i < 196608) {   // gw2t[L][c][hk] = gat_w[L][k][h*128+c]
        int L = i >> 16, rem = i & 65535;
        int c = rem >> 9, hk = rem & 511, hh = hk >> 7, k = hk & 127;
        gwt[i] = f2b(pread(a.gatw,
            (size_t)L * 65536 + (size_t)k * 512 + hh * 128 + c, bf));
        return;
    }
    i -= 196608;
    if (i < 36864) {    // w1t[n=128][k=288] = em1_w[k][n], zero-pad k>=264
        int n = i / 288, k = i - n * 288;
        w1t[i] = (k < 264) ? f2b(pread(a.em1w, (size_t)k * 128 + n, bf)) : 0;
        return;
    }
    i -= 36864;
    if (i < 8192) {     // w2t[n=64][k=128] = em2_w[k][n]
        int n = i >> 7, k = i & 127;
        w2t[i] = f2b(pread(a.em2w, (size_t)k * 64 + n, bf));
    }
}

// ------------------------------------------------------------ va / vat
// One wave per (L,k,j): dot of W[:,h*128+..] column with att row over c=128.
// 3072 waves = 768 blocks. vat[L][j][k]=f2b(dot), vat n>=8 zeroed.
__global__ __launch_bounds__(256) void k_va(
        const void* __restrict__ gatw, const void* __restrict__ asrc,
        const void* __restrict__ adst, const int* __restrict__ flag,
        float* __restrict__ va, unsigned short* __restrict__ vat) {
    int bf = flag[0];
    int id = blockIdx.x * 4 + (threadIdx.x >> 6);
    int lane = threadIdx.x & 63;
    int L = id >> 10, rem = id & 1023;
    int k = rem >> 3, j = rem & 7, hh = j & 3, sd = j >> 2;
    const void* att = sd ? adst : asrc;
    size_t wb = (size_t)L * 65536 + (size_t)k * 512 + hh * 128;
    size_t ab = (size_t)L * 512 + hh * 128;
    int c = lane * 2;
    float s = pread(gatw, wb + c, bf) * pread(att, ab + c, bf)
            + pread(gatw, wb + c + 1, bf) * pread(att, ab + c + 1, bf);
#pragma unroll
    for (int off = 1; off < 64; off <<= 1) s += __shfl_xor(s, off);
    if (lane == 0) {
        va[L * 1024 + k * 8 + j] = s;
        vat[L * 2048 + j * 128 + k] = f2b(s);
    } else if (lane == 1) {
        vat[L * 2048 + (j + 8) * 128 + k] = 0;
    }
}

// ------------------------------------------------------------ graph build
__global__ void k_graph(const int* __restrict__ ei, const int* __restrict__ shock,
                        float* __restrict__ down, int* __restrict__ deg) {
    int e = blockIdx.x * blockDim.x + threadIdx.x;
    if (e < ETOT) {
        int d = (e < N_EDGES) ? ei[N_EDGES + e] : (e - N_EDGES);
        atomicAdd(&deg[d], 1);
        if (e < N_EDGES && shock[ei[e]] != 0) down[d] = 1.f;
    }
}

__global__ __launch_bounds__(1024) void k_scan(
        const int* __restrict__ deg, int* __restrict__ row_start) {
    __shared__ int wsum[16];
    __shared__ int wexcl[16];
    const int PER = 49;
    int t = threadIdx.x, lane = t & 63, wid = t >> 6;
    int base = t * PER;
    int tot = 0;
    for (int i = 0; i < PER; i++) {
        int idx = base + i;
        if (idx < N_NODES) tot += deg[idx];
    }
    int inc = tot;
#pragma unroll
    for (int off = 1; off < 64; off <<= 1) {
        int v = __shfl_up(inc, off);
        if (lane >= off) inc += v;
    }
    if (lane == 63) wsum[wid] = inc;
    __syncthreads();
    if (wid == 0) {
        int wv = (lane < 16) ? wsum[lane] : 0;
        int winc = wv;
#pragma unroll
        for (int off = 1; off < 16; off <<= 1) {
            int v = __shfl_up(winc, off);
            if (lane >= off) winc += v;
        }
        if (lane < 16) wexcl[lane] = winc - wv;
    }
    __syncthreads();
    int run = wexcl[wid] + (inc - tot);
    for (int i = 0; i < PER; i++) {
        int idx = base + i;
        if (idx < N_NODES) {
            row_start[idx] = run;
            run += deg[idx];
        }
    }
    if (t == 0) row_start[N_NODES] = ETOT;
}

__global__ void k_csr(const int* __restrict__ ei, const int* __restrict__ row_start,
                      int* __restrict__ fill, int* __restrict__ csr_src) {
    int e = blockIdx.x * blockDim.x + threadIdx.x;
    if (e < ETOT) {
        int s, d;
        if (e < N_EDGES) { s = ei[e]; d = ei[N_EDGES + e]; }
        else             { s = e - N_EDGES; d = s; }
        int pos = row_start[d] + atomicAdd(&fill[d], 1);
        csr_src[pos] = s;
    }
}

// ------------------------------------------------------------ encoder -> h, al0
// Wave per node. x broadcast via shfl, LN via shfl_xor, al0 from registers.
__global__ __launch_bounds__(256) void k_encoder(
        const void* __restrict__ xraw, const int* __restrict__ flag,
        const int* __restrict__ shock, const float* __restrict__ down,
        const float* __restrict__ enc_w, const float* __restrict__ enc_b,
        const float* __restrict__ ln_g, const float* __restrict__ ln_b,
        const float* __restrict__ va0,
        unsigned short* __restrict__ h, float* __restrict__ al) {
    __shared__ float sw[2304];
    __shared__ float sp[384];
    __shared__ float sva[1024];
    int t = threadIdx.x;
    for (int i = t; i < 2304; i += 256) sw[i] = enc_w[i];
    for (int i = t; i < 1024; i += 256) sva[i] = va0[i];
    if (t < 128)      sp[t] = enc_b[t];
    else if (t < 256) sp[t] = ln_g[t - 128];
    if (t < 128)      sp[256 + t] = ln_b[t];
    __syncthreads();

    int w = t >> 6, l = t & 63;
    int n = blockIdx.x * 4 + w;
    int bf = flag[0];
    int c0 = 2 * l, c1 = c0 + 1;

    float xv = (l < 16) ? pread(xraw, (size_t)n * 16 + l, bf) : 0.f;
    float xs = (float)shock[n];
    float xd = down[n];

    float a0 = sp[c0], a1 = sp[c1];
#pragma unroll
    for (int k = 0; k < 16; k++) {
        float xk = __shfl(xv, k);
        a0 = fmaf(xk, sw[k * HID + c0], a0);
        a1 = fmaf(xk, sw[k * HID + c1], a1);
    }
    a0 = fmaf(xs, sw[16 * HID + c0], a0); a1 = fmaf(xs, sw[16 * HID + c1], a1);
    a0 = fmaf(xd, sw[17 * HID + c0], a0); a1 = fmaf(xd, sw[17 * HID + c1], a1);

    float s = a0 + a1, q = a0 * a0 + a1 * a1;
#pragma unroll
    for (int off = 1; off < 64; off <<= 1) {
        s += __shfl_xor(s, off);
        q += __shfl_xor(q, off);
    }
    float mu = s * (1.f / 128.f);
    float var = q * (1.f / 128.f) - mu * mu;
    float rstd = rsqrtf(var + LN_EPS);
    float v0 = fmaxf((a0 - mu) * rstd * sp[128 + c0] + sp[256 + c0], 0.f);
    float v1 = fmaxf((a1 - mu) * rstd * sp[128 + c1] + sp[256 + c1], 0.f);
    *(unsigned int*)&h[(size_t)n * HID + c0] = pack2(v0, v1);

    float p[8];
#pragma unroll
    for (int j = 0; j < 8; j++)
        p[j] = v0 * sva[c0 * 8 + j] + v1 * sva[c1 * 8 + j];
#pragma unroll
    for (int j = 0; j < 8; j++)
#pragma unroll
        for (int off = 1; off < 64; off <<= 1) p[j] += __shfl_xor(p[j], off);
    if (l < 8) al[(size_t)n * 8 + l] = p[l];
}

// ------------------------------------------------------------ fused GAT layer
// 64 nodes/block. Phase A: each wave aggregates 16 nodes into LDS g-tile
// (stride 520 shorts). Phase B: MFMA gt @ Bt^T, BN epilogue -> h_out.
// Phase C (do_al): h-tile back through LDS, MFMA with vat -> al_out.
__global__ __launch_bounds__(256, 2) void k_layer(
        const unsigned short* __restrict__ h_in, const float* __restrict__ al_in,
        const int* __restrict__ row_start, const int* __restrict__ csr_src,
        const unsigned short* __restrict__ Bt,
        const float* __restrict__ bias,
        const float* __restrict__ bn_g, const float* __restrict__ bn_b,
        const float* __restrict__ bn_m, const float* __restrict__ bn_v,
        const unsigned short* __restrict__ vatL,
        unsigned short* __restrict__ h_out, float* __restrict__ al_out,
        int relu_flag, int do_al) {
    __shared__ __align__(16) unsigned short gt[64 * 520];   // 66560 B
    int t = threadIdx.x;
    int w = t >> 6, l = t & 63, l15 = l & 15, q = l >> 4;
    int m0 = blockIdx.x * 64;

    // ---- phase A: aggregate (wave per node, 16 nodes per wave)
    for (int i = 0; i < 16; i++) {
        int nl = w * 16 + i;
        int n = m0 + nl;
        if (n < N_NODES) {
            int r0 = row_start[n], r1 = row_start[n + 1];
            float4 ad = *(const float4*)(al_in + (size_t)n * 8 + 4);
            float den[4] = {};
            float acc[4][2] = {};
            int s = csr_src[r0];
            float4 as = *(const float4*)(al_in + (size_t)s * 8);
            unsigned int hv = *(const unsigned int*)&h_in[(size_t)s * 128 + 2 * l];
            for (int j = r0; j < r1; j++) {
                int s2 = s; float4 as2 = as; unsigned int hv2 = hv;
                if (j + 1 < r1) {
                    s2 = csr_src[j + 1];
                    as2 = *(const float4*)(al_in + (size_t)s2 * 8);
                    hv2 = *(const unsigned int*)&h_in[(size_t)s2 * 128 + 2 * l];
                }
                float h0 = b2f(hv & 0xffff), h1 = b2f(hv >> 16);
                float lg[4] = {as.x + ad.x, as.y + ad.y, as.z + ad.z, as.w + ad.w};
#pragma unroll
                for (int hh = 0; hh < 4; hh++) {
                    float a = lg[hh];
                    a = (a >= 0.f) ? a : NEG * a;
                    float we = __expf(a);
                    den[hh] += we;
                    acc[hh][0] = fmaf(we, h0, acc[hh][0]);
                    acc[hh][1] = fmaf(we, h1, acc[hh][1]);
                }
                s = s2; as = as2; hv = hv2;
            }
#pragma unroll
            for (int hh = 0; hh < 4; hh++) {
                float sc = 0.25f / (den[hh] + 1e-16f);
                *(unsigned int*)&gt[nl * 520 + hh * 128 + 2 * l] =
                    pack2(acc[hh][0] * sc, acc[hh][1] * sc);
            }
        } else {
#pragma unroll
            for (int hh = 0; hh < 4; hh++)
                *(unsigned int*)&gt[nl * 520 + hh * 128 + 2 * l] = 0u;
        }
    }
    __syncthreads();

    // ---- phase B: GEMM (A = LDS g-tile, B = Bt from L2)
    int c0 = w * 32 + 2 * l15, c1 = c0 + 1;
    v4f acc[4][2] = {};
    for (int kc = 0; kc < 4; kc++) {
        v8s b[2][4];
#pragma unroll
        for (int nt = 0; nt < 2; nt++)
#pragma unroll
            for (int kt = 0; kt < 4; kt++)
                b[nt][kt] = *(const v8s*)&Bt[(size_t)(c0 + nt) * 512
                                             + kc * 128 + kt * 32 + q * 8];
#pragma unroll
        for (int kt = 0; kt < 4; kt++)
#pragma unroll
            for (int mt = 0; mt < 4; mt++) {
                v8s a = *(const v8s*)&gt[(mt * 16 + l15) * 520
                                         + kc * 128 + kt * 32 + q * 8];
                acc[mt][0] = MFMA(a, b[0][kt], acc[mt][0]);
                acc[mt][1] = MFMA(a, b[1][kt], acc[mt][1]);
            }
    }

    float rs0 = rsqrtf(bn_v[c0] + LN_EPS) * bn_g[c0];
    float sh0 = bn_b[c0] + (bias[c0] - bn_m[c0]) * rs0;
    float rs1 = rsqrtf(bn_v[c1] + LN_EPS) * bn_g[c1];
    float sh1 = bn_b[c1] + (bias[c1] - bn_m[c1]) * rs1;
    unsigned int hp[4][4];
#pragma unroll
    for (int mt = 0; mt < 4; mt++)
#pragma unroll
        for (int r = 0; r < 4; r++) {
            float v0 = acc[mt][0][r] * rs0 + sh0;
            float v1 = acc[mt][1][r] * rs1 + sh1;
            if (relu_flag) { v0 = fmaxf(v0, 0.f); v1 = fmaxf(v1, 0.f); }
            hp[mt][r] = pack2(v0, v1);
            int node = m0 + mt * 16 + q * 4 + r;
            if (node < N_NODES)
                *(unsigned int*)&h_out[(size_t)node * 128 + c0] = hp[mt][r];
        }

    // ---- phase C: next-layer logits (al_out = h_tile @ vat)
    if (do_al) {
        __syncthreads();   // all gt reads done
#pragma unroll
        for (int mt = 0; mt < 4; mt++)
#pragma unroll
            for (int r = 0; r < 4; r++)
                *(unsigned int*)&gt[(mt * 16 + q * 4 + r) * 520 + c0] = hp[mt][r];
        __syncthreads();
        v8s bv[4];
#pragma unroll
        for (int kt = 0; kt < 4; kt++)
            bv[kt] = *(const v8s*)&vatL[l15 * 128 + kt * 32 + q * 8];
        v4f aal = {};
#pragma unroll
        for (int kt = 0; kt < 4; kt++) {
            v8s a = *(const v8s*)&gt[(w * 16 + l15) * 520 + kt * 32 + q * 8];
            aal = MFMA(a, bv[kt], aal);
        }
        if (l15 < 8) {
#pragma unroll
            for (int r = 0; r < 4; r++) {
                int node = m0 + w * 16 + q * 4 + r;
                if (node < N_NODES) al_out[(size_t)node * 8 + l15] = aal[r];
            }
        }
    }
}

// ------------------------------------------------------------ edge MLP (MFMA)
__global__ __launch_bounds__(256, 4) void k_edgemlp(
        const unsigned short* __restrict__ h, const int* __restrict__ ei,
        const void* __restrict__ eraw, const int* __restrict__ flag,
        const unsigned short* __restrict__ w1t, const unsigned short* __restrict__ w2t,
        const float* __restrict__ em1b, const float* __restrict__ lng,
        const float* __restrict__ lnb, const float* __restrict__ em2b,
        const float* __restrict__ em3w, const float* __restrict__ em3b,
        float* __restrict__ out) {
    __shared__ __align__(16) unsigned short in_s[64 * 296];
    __shared__ float sums[64][4][2];
    __shared__ float stats[64][2];
    __shared__ int   idx_s[128];
    unsigned short* za = in_s;
    float* part = &sums[0][0][0];

    int t = threadIdx.x;
    int lane = t & 63, w = t >> 6, l15 = lane & 15, q = lane >> 4;
    int e0 = blockIdx.x * 64;
    int bf = flag[0];
    int c0 = w * 32 + 2 * l15, c1 = c0 + 1;

    v8s b1[2][9];
#pragma unroll
    for (int nt = 0; nt < 2; nt++)
#pragma unroll
        for (int kt = 0; kt < 9; kt++)
            b1[nt][kt] = *(const v8s*)&w1t[(size_t)(c0 + nt) * 288 + kt * 32 + q * 8];
    v8s b2[4];
#pragma unroll
    for (int kt = 0; kt < 4; kt++)
        b2[kt] = *(const v8s*)&w2t[(size_t)(w * 16 + l15) * 128 + kt * 32 + q * 8];

    float bc0 = em1b[c0], bc1 = em1b[c1];
    float lg0 = lng[c0], lg1 = lng[c1], lb0 = lnb[c0], lb1 = lnb[c1];

    if (t < 64) {
        idx_s[t * 2]     = ei[e0 + t];
        idx_s[t * 2 + 1] = ei[N_EDGES + e0 + t];
    }
    __syncthreads();

    for (int idx = t; idx < 64 * 36; idx += 256) {
        int row = idx / 36, c = idx - row * 36;
        v8s val = {0, 0, 0, 0, 0, 0, 0, 0};
        if (c < 32) {
            int node = idx_s[row * 2 + (c >> 4)];
            val = *(const v8s*)&h[(size_t)node * 128 + (c & 15) * 8];
        } else if (c == 32) {
            size_t eb = (size_t)(e0 + row) * 8;
            if (bf) {
                val = *(const v8s*)((const unsigned short*)eraw + eb);
            } else {
                short tmp[8];
#pragma unroll
                for (int j = 0; j < 8; j++)
                    tmp[j] = (short)f2b(((const float*)eraw)[eb + j]);
                val = *(const v8s*)tmp;
            }
        }
        *(v8s*)&in_s[row * 296 + c * 8] = val;
    }
    __syncthreads();

    v4f acc1[4][2] = {};
#pragma unroll
    for (int kt = 0; kt < 9; kt++)
#pragma unroll
        for (int mt = 0; mt < 4; mt++) {
            v8s a = *(const v8s*)&in_s[(mt * 16 + l15) * 296 + kt * 32 + q * 8];
            acc1[mt][0] = MFMA(a, b1[0][kt], acc1[mt][0]);
            acc1[mt][1] = MFMA(a, b1[1][kt], acc1[mt][1]);
        }

#pragma unroll
    for (int mt = 0; mt < 4; mt++)
#pragma unroll
        for (int r = 0; r < 4; r++) {
            float v0 = acc1[mt][0][r] + bc0;
            float v1 = acc1[mt][1][r] + bc1;
            float s = v0 + v1;
            float qq = v0 * v0 + v1 * v1;
#pragma unroll
            for (int off = 1; off < 16; off <<= 1) {
                s  += __shfl_xor(s, off);
                qq += __shfl_xor(qq, off);
            }
            if (l15 == 0) {
                sums[mt * 16 + q * 4 + r][w][0] = s;
                sums[mt * 16 + q * 4 + r][w][1] = qq;
            }
        }
    __syncthreads();
    if (t < 64) {
        float S = sums[t][0][0] + sums[t][1][0] + sums[t][2][0] + sums[t][3][0];
        float Q = sums[t][0][1] + sums[t][1][1] + sums[t][2][1] + sums[t][3][1];
        float mu = S * (1.f / 128.f);
        float var = Q * (1.f / 128.f) - mu * mu;
        stats[t][0] = mu;
        stats[t][1] = rsqrtf(var + LN_EPS);
    }
    __syncthreads();

#pragma unroll
    for (int mt = 0; mt < 4; mt++)
#pragma unroll
        for (int r = 0; r < 4; r++) {
            int row = mt * 16 + q * 4 + r;
            float mu = stats[row][0], rstd = stats[row][1];
            float z0 = (acc1[mt][0][r] + bc0 - mu) * rstd * lg0 + lb0;
            float z1 = (acc1[mt][1][r] + bc1 - mu) * rstd * lg1 + lb1;
            *(unsigned int*)&za[row * 136 + c0] =
                pack2(fmaxf(z0, 0.f), fmaxf(z1, 0.f));
        }
    __syncthreads();

    v4f acc2[4] = {};
#pragma unroll
    for (int kt = 0; kt < 4; kt++)
#pragma unroll
        for (int mt = 0; mt < 4; mt++) {
            v8s a = *(const v8s*)&za[(mt * 16 + l15) * 136 + kt * 32 + q * 8];
            acc2[mt] = MFMA(a, b2[kt], acc2[mt]);
        }
    __syncthreads();

    {
        int col = w * 16 + l15;
        float b2c = em2b[col], w3c = em3w[col];
#pragma unroll
        for (int mt = 0; mt < 4; mt++)
#pragma unroll
            for (int r = 0; r < 4; r++) {
                float v = fmaxf(acc2[mt][r] + b2c, 0.f) * w3c;
#pragma unroll
                for (int off = 1; off < 16; off <<= 1) v += __shfl_xor(v, off);
                if (l15 == 0) part[w * 64 + mt * 16 + q * 4 + r] = v;
            }
    }
    __syncthreads();
    if (t < 64)
        out[e0 + t] = part[t] + part[64 + t] + part[128 + t] + part[192 + t]
                    + em3b[0];
}

// ------------------------------------------------------------ launch
extern "C" __attribute__((visibility("default")))
void kernel_launch(void* const* d_in, const int* in_sizes, int n_in,
                   void* d_out, int out_size, void* d_ws, size_t ws_size,
                   hipStream_t stream) {
    float* out = (float*)d_out;

    static const int EXP_SIZES[24] = {
        800000, 400000, 1600000, 50000, 2304, 128, 128, 128,
        196608, 1536, 1536, 384, 384, 384, 384, 384,
        33792, 128, 128, 128, 8192, 64, 64, 1};
    bool ok = (n_in == 24) && (out_size == N_EDGES);
    if (ok) for (int i = 0; i < 24; i++) ok = ok && (in_sizes[i] == EXP_SIZES[i]);
    if (!ok) {
        k_fill<<<(out_size + 255) / 256, 256, 0, stream>>>(out, out_size, 4.0f);
        return;
    }
    if (ws_size < (size_t)40000000) {
        k_fill<<<(out_size + 255) / 256, 256, 0, stream>>>(out, out_size, 8.0f);
        return;
    }

    const int* ei    = (const int*)d_in[1];
    const int* shock = (const int*)d_in[3];

    char* ws = (char*)d_ws;
    unsigned short* h0 = (unsigned short*)(ws + 0);          // 12,800,000
    unsigned short* h1 = (unsigned short*)(ws + 12800000);   // 12,800,000
    float* al0     = (float*)(ws + 25600000);                // 1,600,000
    float* al1     = (float*)(ws + 27200000);                // 1,600,000
    float* down    = (float*)(ws + 28800000);                // 200,000
    int*   deg     = (int*)  (ws + 29000000);                // 200,000
    int*   row_st  = (int*)  (ws + 29200000);                // 200,064
    int*   fill    = (int*)  (ws + 29400064);                // 200,000
    int*   csr_src = (int*)  (ws + 29600064);                // 1,000,000
    int*   flag    = (int*)  (ws + 30600064);                // 64
    unsigned short* gwt = (unsigned short*)(ws + 30600128);  // 393,216
    unsigned short* w1t = (unsigned short*)(ws + 30993344);  // 73,728
    unsigned short* w2t = (unsigned short*)(ws + 31067072);  // 16,384
    float* pool    = (float*)(ws + 31083456);                // 11,272 f32
    unsigned short* vat = (unsigned short*)(ws + 31128544);  // 12,288 B

    float* cencw = pool + 0;    float* cencb = pool + 2304;
    float* cenlg = pool + 2432; float* cenlb = pool + 2560;
    float* cbias = pool + 5760; float* cbng  = pool + 6144;
    float* cbnb  = pool + 6528; float* cbnm  = pool + 6912;
    float* cbnv  = pool + 7296; float* cem1b = pool + 7680;
    float* cemlg = pool + 7808; float* cemlb = pool + 7936;
    float* cem2b = pool + 8064; float* cem3w = pool + 8128;
    float* cem3b = pool + 8192;
    float* va    = pool + 8200;    // [3][128][8]

    k_detect<<<1, 64, 0, stream>>>((const unsigned short*)d_in[0], flag);

    PrepArgs pa;
    pa.encw = d_in[4];  pa.encb = d_in[5];  pa.enlg = d_in[6];  pa.enlb = d_in[7];
    pa.gatw = d_in[8];  pa.asrc = d_in[9];  pa.adst = d_in[10]; pa.bias = d_in[11];
    pa.bng  = d_in[12]; pa.bnb  = d_in[13]; pa.bnm  = d_in[14]; pa.bnv  = d_in[15];
    pa.em1w = d_in[16]; pa.em1b = d_in[17]; pa.emlg = d_in[18]; pa.emlb = d_in[19];
    pa.em2w = d_in[20]; pa.em2b = d_in[21]; pa.em3w = d_in[22]; pa.em3b = d_in[23];
    k_prep<<<(PREP_ITEMS + 255) / 256, 256, 0, stream>>>(
        pa, pool, gwt, w1t, w2t, down, deg, fill, flag);
    k_va<<<768, 256, 0, stream>>>(d_in[8], d_in[9], d_in[10], flag, va, vat);

    k_graph<<<(ETOT + 255) / 256, 256, 0, stream>>>(ei, shock, down, deg);
    k_scan<<<1, 1024, 0, stream>>>(deg, row_st);
    k_csr<<<(ETOT + 255) / 256, 256, 0, stream>>>(ei, row_st, fill, csr_src);
    k_encoder<<<N_NODES / 4, 256, 0, stream>>>(
        d_in[0], flag, shock, down, cencw, cencb, cenlg, cenlb, va, h0, al0);

    unsigned short* hbuf[2] = {h0, h1};
    float* albuf[2] = {al0, al1};
    for (int i = 0; i < 3; i++) {
        k_layer<<<(N_NODES + 63) / 64, 256, 0, stream>>>(
            hbuf[i & 1], albuf[i & 1], row_st, csr_src,
            gwt + (size_t)i * 65536, cbias + i * 128,
            cbng + i * 128, cbnb + i * 128, cbnm + i * 128, cbnv + i * 128,
            vat + (size_t)(i + 1 < 3 ? i + 1 : 0) * 2048,
            hbuf[(i + 1) & 1], albuf[(i + 1) & 1],
            (i < 2) ? 1 : 0, (i < 2) ? 1 : 0);
    }
    k_edgemlp<<<N_EDGES / 64, 256, 0, stream>>>(
        hbuf[1], ei, d_in[2], flag, w1t, w2t,
        cem1b, cemlg, cemlb, cem2b, cem3w, cem3b, out);
}

// Round 11
// 571.971 us; speedup vs baseline: 1.4131x; 1.4131x over previous
//
#include <hip/hip_runtime.h>
#include <hip/hip_bf16.h>

// ShockPropagationGNN — round 10: revert to round-5 structure (measured best)
// + wave-per-node encoder + edge-MLP U/V split:
//   z_pre[e] = U[src] + V[dst] + ea@W1e + b1,  U|V = h @ em1_w[0:256] (MFMA).
// k_edgemlp2: 2 coalesced row-gathers/edge, in-wave LN, layer-2 MFMA only.

#define N_NODES 50000
#define N_EDGES 200000
#define ETOT    (N_EDGES + N_NODES)
#define HID     128
#define LN_EPS  1e-5f
#define NEG     0.2f

typedef __hip_bfloat16 bf16;
typedef __attribute__((ext_vector_type(8))) short v8s;
typedef __attribute__((ext_vector_type(4))) float v4f;
#define MFMA(a, b, c) __builtin_amdgcn_mfma_f32_16x16x32_bf16(a, b, c, 0, 0, 0)

__device__ __forceinline__ float b2f(unsigned short s) {
    return __uint_as_float(((unsigned int)s) << 16);
}
__device__ __forceinline__ unsigned short f2b(float f) {
    __hip_bfloat16 h = __float2bfloat16(f);
    return *reinterpret_cast<unsigned short*>(&h);
}
__device__ __forceinline__ unsigned int pack2(float a, float b) {
    return (unsigned int)f2b(a) | ((unsigned int)f2b(b) << 16);
}
__device__ __forceinline__ float pread(const void* p, size_t i, int isbf) {
    if (isbf) return b2f(((const unsigned short*)p)[i]);
    return ((const float*)p)[i];
}

__global__ void k_fill(float* out, int n, float v) {
    int i = blockIdx.x * blockDim.x + threadIdx.x;
    if (i < n) out[i] = v;
}

// ------------------------------------------------------------ dtype detect
__global__ void k_detect(const unsigned short* __restrict__ xbuf,
                         int* __restrict__ flag) {
    int sane = 0;
    for (int j = threadIdx.x; j < 4096; j += 64) {
        unsigned short v = xbuf[2 * j];
        int e = (v >> 7) & 0xFF;
        if (v == 0 || (e > 96 && e < 160)) sane++;
    }
    for (int off = 32; off > 0; off >>= 1) sane += __shfl_down(sane, off);
    if (threadIdx.x == 0) flag[0] = (sane * 10 >= 4096 * 9) ? 1 : 0;
}

// ------------------------------------------------------------ prep (fused)
struct PrepArgs {
    const void *encw, *encb, *enlg, *enlb, *gatw, *asrc, *adst, *bias,
               *bng, *bnb, *bnm, *bnv, *em1w, *em1b, *emlg, *emlb,
               *em2w, *em2b, *em3w, *em3b;
};
// zeros | pool | w1e | gwt | uvt | w2t
#define PREP_ITEMS (150000 + 8193 + 1024 + 196608 + 32768 + 8192)
__global__ void k_prep(PrepArgs a, float* __restrict__ pool,
                       unsigned short* __restrict__ gwt,   // [L][n=512][k=128]
                       unsigned short* __restrict__ uvt,   // [n=256][k=128]
                       unsigned short* __restrict__ w2t,   // [n=64][k=128]
                       float* __restrict__ down, int* __restrict__ deg,
                       int* __restrict__ fill, const int* __restrict__ flag) {
    int i = blockIdx.x * 256 + threadIdx.x;
    int bf = flag[0];
    if (i < 150000) {
        int which = i / 50000, idx = i - which * 50000;
        if (which == 0) down[idx] = 0.f;
        else if (which == 1) deg[idx] = 0;
        else fill[idx] = 0;
        return;
    }
    i -= 150000;
    if (i < 8193) {
        const void* s; int off;
        if      (i < 2304) { s = a.encw; off = 0;    }
        else if (i < 2432) { s = a.encb; off = 2304; }
        else if (i < 2560) { s = a.enlg; off = 2432; }
        else if (i < 2688) { s = a.enlb; off = 2560; }
        else if (i < 4224) { s = a.asrc; off = 2688; }
        else if (i < 5760) { s = a.adst; off = 4224; }
        else if (i < 6144) { s = a.bias; off = 5760; }
        else if (i < 6528) { s = a.bng;  off = 6144; }
        else if (i < 6912) { s = a.bnb;  off = 6528; }
        else if (i < 7296) { s = a.bnm;  off = 6912; }
        else if (i < 7680) { s = a.bnv;  off = 7296; }
        else if (i < 7808) { s = a.em1b; off = 7680; }
        else if (i < 7936) { s = a.emlg; off = 7808; }
        else if (i < 8064) { s = a.emlb; off = 7936; }
        else if (i < 8128) { s = a.em2b; off = 8064; }
        else if (i < 8192) { s = a.em3w; off = 8128; }
        else               { s = a.em3b; off = 8192; }
        pool[i] = pread(s, i - off, bf);
        return;
    }
    i -= 8193;
    if (i < 1024) {     // w1e fp32: pool[8200 + k*128+c] = em1_w[256+k][c]
        int k = i >> 7, c = i & 127;
        pool[8200 + i] = pread(a.em1w, (size_t)(256 + k) * 128 + c, bf);
        return;
    }
    i -= 1024;
    if (i < 196608) {   // gwt[L][n][k] = gat_w[L][k][n]
        int L = i >> 16, rem = i & 65535, n = rem >> 7, k = rem & 127;
        gwt[i] = f2b(pread(a.gatw, (size_t)L * 65536 + (size_t)k * 512 + n, bf));
        return;
    }
    i -= 196608;
    if (i < 32768) {    // uvt[n][k]: n<128 -> em1_w[k][n]; else em1_w[128+k][n-128]
        int n = i >> 7, k = i & 127;
        float v = (n < 128) ? pread(a.em1w, (size_t)k * 128 + n, bf)
                            : pread(a.em1w, (size_t)(128 + k) * 128 + (n - 128), bf);
        uvt[i] = f2b(v);
        return;
    }
    i -= 32768;
    if (i < 8192) {     // w2t[n][k] = em2_w[k][n]
        int n = i >> 7, k = i & 127;
        w2t[i] = f2b(pread(a.em2w, (size_t)k * 64 + n, bf));
    }
}

// ------------------------------------------------------------ graph build
__global__ void k_graph(const int* __restrict__ ei, const int* __restrict__ shock,
                        float* __restrict__ down, int* __restrict__ deg) {
    int e = blockIdx.x * blockDim.x + threadIdx.x;
    if (e < ETOT) {
        int d = (e < N_EDGES) ? ei[N_EDGES + e] : (e - N_EDGES);
        atomicAdd(&deg[d], 1);
        if (e < N_EDGES && shock[ei[e]] != 0) down[d] = 1.f;
    }
}

__global__ __launch_bounds__(1024) void k_scan(
        const int* __restrict__ deg, int* __restrict__ row_start) {
    __shared__ int wsum[16];
    __shared__ int wexcl[16];
    const int PER = 49;
    int t = threadIdx.x, lane = t & 63, wid = t >> 6;
    int base = t * PER;
    int tot = 0;
    for (int i = 0; i < PER; i++) {
        int idx = base + i;
        if (idx < N_NODES) tot += deg[idx];
    }
    int inc = tot;
#pragma unroll
    for (int off = 1; off < 64; off <<= 1) {
        int v = __shfl_up(inc, off);
        if (lane >= off) inc += v;
    }
    if (lane == 63) wsum[wid] = inc;
    __syncthreads();
    if (wid == 0) {
        int wv = (lane < 16) ? wsum[lane] : 0;
        int winc = wv;
#pragma unroll
        for (int off = 1; off < 16; off <<= 1) {
            int v = __shfl_up(winc, off);
            if (lane >= off) winc += v;
        }
        if (lane < 16) wexcl[lane] = winc - wv;
    }
    __syncthreads();
    int run = wexcl[wid] + (inc - tot);
    for (int i = 0; i < PER; i++) {
        int idx = base + i;
        if (idx < N_NODES) {
            row_start[idx] = run;
            run += deg[idx];
        }
    }
    if (t == 0) row_start[N_NODES] = ETOT;
}

__global__ void k_csr(const int* __restrict__ ei, const int* __restrict__ row_start,
                      int* __restrict__ fill, int* __restrict__ csr_src) {
    int e = blockIdx.x * blockDim.x + threadIdx.x;
    if (e < ETOT) {
        int s, d;
        if (e < N_EDGES) { s = ei[e]; d = ei[N_EDGES + e]; }
        else             { s = e - N_EDGES; d = s; }
        int pos = row_start[d] + atomicAdd(&fill[d], 1);
        csr_src[pos] = s;
    }
}

// ------------------------------------------------------------ encoder -> h bf16
// Wave per node; x broadcast via shfl, LN via shfl_xor, packed u32 stores.
__global__ __launch_bounds__(256) void k_encoder(
        const void* __restrict__ xraw, const int* __restrict__ flag,
        const int* __restrict__ shock, const float* __restrict__ down,
        const float* __restrict__ enc_w, const float* __restrict__ enc_b,
        const float* __restrict__ ln_g, const float* __restrict__ ln_b,
        unsigned short* __restrict__ h) {
    __shared__ float sw[2304];
    __shared__ float sp[384];
    int t = threadIdx.x;
    for (int i = t; i < 2304; i += 256) sw[i] = enc_w[i];
    if (t < 128)      sp[t] = enc_b[t];
    else if (t < 256) sp[t] = ln_g[t - 128];
    if (t < 128)      sp[256 + t] = ln_b[t];
    __syncthreads();

    int w = t >> 6, l = t & 63;
    int n = blockIdx.x * 4 + w;
    int bf = flag[0];
    int c0 = 2 * l, c1 = c0 + 1;

    float xv = (l < 16) ? pread(xraw, (size_t)n * 16 + l, bf) : 0.f;
    float xs = (float)shock[n];
    float xd = down[n];

    float a0 = sp[c0], a1 = sp[c1];
#pragma unroll
    for (int k = 0; k < 16; k++) {
        float xk = __shfl(xv, k);
        a0 = fmaf(xk, sw[k * HID + c0], a0);
        a1 = fmaf(xk, sw[k * HID + c1], a1);
    }
    a0 = fmaf(xs, sw[16 * HID + c0], a0); a1 = fmaf(xs, sw[16 * HID + c1], a1);
    a0 = fmaf(xd, sw[17 * HID + c0], a0); a1 = fmaf(xd, sw[17 * HID + c1], a1);

    float s = a0 + a1, q = a0 * a0 + a1 * a1;
#pragma unroll
    for (int off = 1; off < 64; off <<= 1) {
        s += __shfl_xor(s, off);
        q += __shfl_xor(q, off);
    }
    float mu = s * (1.f / 128.f);
    float var = q * (1.f / 128.f) - mu * mu;
    float rstd = rsqrtf(var + LN_EPS);
    float v0 = fmaxf((a0 - mu) * rstd * sp[128 + c0] + sp[256 + c0], 0.f);
    float v1 = fmaxf((a1 - mu) * rstd * sp[128 + c1] + sp[256 + c1], 0.f);
    *(unsigned int*)&h[(size_t)n * HID + c0] = pack2(v0, v1);
}

// ------------------------------------------------------------ GAT GEMM + logits
// (round-5 verbatim) xh = h @ W, logits reduced in-block (block = one head).
__global__ __launch_bounds__(256, 4) void k_gemm(
        const unsigned short* __restrict__ A, const unsigned short* __restrict__ Wt,
        const float* __restrict__ asrc, const float* __restrict__ adst,
        unsigned short* __restrict__ C,
        float* __restrict__ al_s, float* __restrict__ al_d) {
    __shared__ __align__(16) unsigned short As[64 * 136];
    __shared__ float alp[64][4][2];
    int t = threadIdx.x;
    int lane = t & 63, w = t >> 6, l15 = lane & 15, q = lane >> 4;
    int m0 = blockIdx.x * 64, n0 = blockIdx.y * 128, head = blockIdx.y;
    int c0 = n0 + w * 32 + 2 * l15, c1 = c0 + 1;

    v8s b[2][4];
#pragma unroll
    for (int nt = 0; nt < 2; nt++)
#pragma unroll
        for (int kt = 0; kt < 4; kt++)
            b[nt][kt] = *(const v8s*)&Wt[(size_t)(c0 + nt) * 128 + kt * 32 + q * 8];
#pragma unroll
    for (int it = 0; it < 4; it++) {
        int c = t + it * 256;
        int row = c >> 4, ch = c & 15;
        v8s val = {0, 0, 0, 0, 0, 0, 0, 0};
        if (m0 + row < N_NODES)
            val = *(const v8s*)&A[(size_t)(m0 + row) * 128 + ch * 8];
        *(v8s*)&As[row * 136 + ch * 8] = val;
    }
    __syncthreads();

    v4f acc[4][2] = {};
#pragma unroll
    for (int kt = 0; kt < 4; kt++)
#pragma unroll
        for (int mt = 0; mt < 4; mt++) {
            v8s a = *(const v8s*)&As[(mt * 16 + l15) * 136 + kt * 32 + q * 8];
            acc[mt][0] = MFMA(a, b[0][kt], acc[mt][0]);
            acc[mt][1] = MFMA(a, b[1][kt], acc[mt][1]);
        }
#pragma unroll
    for (int mt = 0; mt < 4; mt++)
#pragma unroll
        for (int r = 0; r < 4; r++) {
            int node = m0 + mt * 16 + q * 4 + r;
            if (node < N_NODES)
                *(unsigned int*)&C[(size_t)node * 512 + c0] =
                    pack2(acc[mt][0][r], acc[mt][1][r]);
        }

    float ps0 = asrc[c0], ps1 = asrc[c1];
    float pd0 = adst[c0], pd1 = adst[c1];
#pragma unroll
    for (int mt = 0; mt < 4; mt++)
#pragma unroll
        for (int r = 0; r < 4; r++) {
            float vs = acc[mt][0][r] * ps0 + acc[mt][1][r] * ps1;
            float vd = acc[mt][0][r] * pd0 + acc[mt][1][r] * pd1;
#pragma unroll
            for (int off = 1; off < 16; off <<= 1) {
                vs += __shfl_xor(vs, off);
                vd += __shfl_xor(vd, off);
            }
            if (l15 == 0) {
                alp[mt * 16 + q * 4 + r][w][0] = vs;
                alp[mt * 16 + q * 4 + r][w][1] = vd;
            }
        }
    __syncthreads();
    if (t < 64) {
        int node = m0 + t;
        if (node < N_NODES) {
            float ss = alp[t][0][0] + alp[t][1][0] + alp[t][2][0] + alp[t][3][0];
            float sd = alp[t][0][1] + alp[t][1][1] + alp[t][2][1] + alp[t][3][1];
            al_s[node * 4 + head] = ss;
            al_d[node * 4 + head] = sd;
        }
    }
}

// ------------------------------------------------------------ aggregation
// (round-5 verbatim) wave per node, single-pass softmax over xh gather.
__global__ __launch_bounds__(256) void k_aggregate(
        const unsigned short* __restrict__ xh, const float* __restrict__ al_src,
        const float* __restrict__ al_dst,
        const int* __restrict__ row_start, const int* __restrict__ csr_src,
        const float* __restrict__ bias,
        const float* __restrict__ bn_g, const float* __restrict__ bn_b,
        const float* __restrict__ bn_m, const float* __restrict__ bn_v,
        unsigned short* __restrict__ h, int relu_flag) {
    int w = threadIdx.x >> 6, l = threadIdx.x & 63;
    int n = blockIdx.x * 4 + w;
    int hh = l >> 4, c8 = l & 15;
    int r0 = row_start[n], r1 = row_start[n + 1];
    float ad = al_dst[n * 4 + hh];
    float sh = 0.f;
    float acc[8] = {};
    for (int j = r0; j < r1; j++) {
        int s = csr_src[j];
        float a = al_src[s * 4 + hh] + ad;
        a = (a >= 0.f) ? a : NEG * a;
        float we = __expf(a);
        sh += we;
        v8s row = *(const v8s*)&xh[(size_t)s * 512 + l * 8];
#pragma unroll
        for (int i = 0; i < 8; i++)
            acc[i] = fmaf(we, b2f((unsigned short)row[i]), acc[i]);
    }
    float inv = 1.f / (sh + 1e-16f);
#pragma unroll
    for (int i = 0; i < 8; i++) {
        acc[i] *= inv;
        acc[i] += __shfl_xor(acc[i], 16);
        acc[i] += __shfl_xor(acc[i], 32);
    }
    if (hh == 0) {
        int cbase = c8 * 8;
        short o[8];
#pragma unroll
        for (int i = 0; i < 8; i++) {
            int c = cbase + i;
            float v = 0.25f * acc[i] + bias[c];
            v = (v - bn_m[c]) * rsqrtf(bn_v[c] + LN_EPS) * bn_g[c] + bn_b[c];
            if (relu_flag) v = fmaxf(v, 0.f);
            o[i] = (short)f2b(v);
        }
        *(v8s*)&h[(size_t)n * 128 + cbase] = *(const v8s*)o;
    }
}

// ------------------------------------------------------------ UV GEMM
// UV[50000,256] = h[50000,128] @ em1_w[0:256]^T (U cols 0..127, V 128..255).
__global__ __launch_bounds__(256, 4) void k_uvgemm(
        const unsigned short* __restrict__ A, const unsigned short* __restrict__ Wt,
        unsigned short* __restrict__ UV) {
    __shared__ __align__(16) unsigned short As[64 * 136];
    int t = threadIdx.x;
    int lane = t & 63, w = t >> 6, l15 = lane & 15, q = lane >> 4;
    int m0 = blockIdx.x * 64, n0 = blockIdx.y * 128;
    int c0 = n0 + w * 32 + 2 * l15;

    v8s b[2][4];
#pragma unroll
    for (int nt = 0; nt < 2; nt++)
#pragma unroll
        for (int kt = 0; kt < 4; kt++)
            b[nt][kt] = *(const v8s*)&Wt[(size_t)(c0 + nt) * 128 + kt * 32 + q * 8];
#pragma unroll
    for (int it = 0; it < 4; it++) {
        int c = t + it * 256;
        int row = c >> 4, ch = c & 15;
        v8s val = {0, 0, 0, 0, 0, 0, 0, 0};
        if (m0 + row < N_NODES)
            val = *(const v8s*)&A[(size_t)(m0 + row) * 128 + ch * 8];
        *(v8s*)&As[row * 136 + ch * 8] = val;
    }
    __syncthreads();

    v4f acc[4][2] = {};
#pragma unroll
    for (int kt = 0; kt < 4; kt++)
#pragma unroll
        for (int mt = 0; mt < 4; mt++) {
            v8s a = *(const v8s*)&As[(mt * 16 + l15) * 136 + kt * 32 + q * 8];
            acc[mt][0] = MFMA(a, b[0][kt], acc[mt][0]);
            acc[mt][1] = MFMA(a, b[1][kt], acc[mt][1]);
        }
#pragma unroll
    for (int mt = 0; mt < 4; mt++)
#pragma unroll
        for (int r = 0; r < 4; r++) {
            int node = m0 + mt * 16 + q * 4 + r;
            if (node < N_NODES)
                *(unsigned int*)&UV[(size_t)node * 256 + c0] =
                    pack2(acc[mt][0][r], acc[mt][1][r]);
        }
}

// ------------------------------------------------------------ edge MLP v2
// 64 edges/block, wave w handles 16 edges serially (prefetched U/V rows).
// z = relu(LN(U[src]+V[dst]+ea@W1e+b1)) -> za; layer2 MFMA; dot em3.
__global__ __launch_bounds__(256) void k_edgemlp2(
        const unsigned short* __restrict__ UV, const int* __restrict__ ei,
        const void* __restrict__ eraw, const int* __restrict__ flag,
        const float* __restrict__ w1e, const float* __restrict__ em1b,
        const float* __restrict__ lng, const float* __restrict__ lnb,
        const unsigned short* __restrict__ w2t, const float* __restrict__ em2b,
        const float* __restrict__ em3w, const float* __restrict__ em3b,
        float* __restrict__ out) {
    __shared__ __align__(16) unsigned short za[64 * 136];   // 17408 B
    __shared__ float w1e_s[1024];                           // 4096 B
    __shared__ unsigned short ea_s[64 * 8];                 // 1024 B
    __shared__ int idx_s[128];
    __shared__ float part[4][64];

    int t = threadIdx.x;
    int lane = t & 63, w = t >> 6, l15 = lane & 15, q = lane >> 4;
    int e0 = blockIdx.x * 64;
    int bf = flag[0];

    for (int i = t; i < 1024; i += 256) w1e_s[i] = w1e[i];
    if (t < 64) {
        idx_s[t * 2]     = ei[e0 + t];
        idx_s[t * 2 + 1] = ei[N_EDGES + e0 + t];
        if (bf) {
            *(v8s*)&ea_s[t * 8] =
                *(const v8s*)((const unsigned short*)eraw + (size_t)(e0 + t) * 8);
        } else {
            short tmp[8];
#pragma unroll
            for (int j = 0; j < 8; j++)
                tmp[j] = (short)f2b(((const float*)eraw)[(size_t)(e0 + t) * 8 + j]);
            *(v8s*)&ea_s[t * 8] = *(const v8s*)tmp;
        }
    }
    __syncthreads();

    int c0 = 2 * lane, c1 = c0 + 1;
    float bc0 = em1b[c0], bc1 = em1b[c1];
    float lg0 = lng[c0], lg1 = lng[c1], lb0 = lnb[c0], lb1 = lnb[c1];

    // prefetch first edge of this wave
    int el0 = w * 16;
    unsigned int u = *(const unsigned int*)&UV[(size_t)idx_s[el0 * 2] * 256 + c0];
    unsigned int v = *(const unsigned int*)&UV[(size_t)idx_s[el0 * 2 + 1] * 256 + 128 + c0];
#pragma unroll 1
    for (int i = 0; i < 16; i++) {
        int el = w * 16 + i;
        unsigned int uc = u, vc = v;
        if (i < 15) {
            int el2 = el + 1;
            u = *(const unsigned int*)&UV[(size_t)idx_s[el2 * 2] * 256 + c0];
            v = *(const unsigned int*)&UV[(size_t)idx_s[el2 * 2 + 1] * 256 + 128 + c0];
        }
        float e0t = 0.f, e1t = 0.f;
#pragma unroll
        for (int k = 0; k < 8; k++) {
            float eak = b2f(ea_s[el * 8 + k]);
            e0t = fmaf(eak, w1e_s[k * 128 + c0], e0t);
            e1t = fmaf(eak, w1e_s[k * 128 + c1], e1t);
        }
        float z0 = b2f(uc & 0xffff) + b2f(vc & 0xffff) + e0t + bc0;
        float z1 = b2f(uc >> 16) + b2f(vc >> 16) + e1t + bc1;
        float s = z0 + z1, qq = z0 * z0 + z1 * z1;
#pragma unroll
        for (int off = 1; off < 64; off <<= 1) {
            s  += __shfl_xor(s, off);
            qq += __shfl_xor(qq, off);
        }
        float mu = s * (1.f / 128.f);
        float var = qq * (1.f / 128.f) - mu * mu;
        float rstd = rsqrtf(var + LN_EPS);
        float y0 = fmaxf((z0 - mu) * rstd * lg0 + lb0, 0.f);
        float y1 = fmaxf((z1 - mu) * rstd * lg1 + lb1, 0.f);
        *(unsigned int*)&za[el * 136 + c0] = pack2(y0, y1);
    }
    __syncthreads();

    // layer 2 MFMA: wave w -> cols w*16..+15
    v8s b2[4];
#pragma unroll
    for (int kt = 0; kt < 4; kt++)
        b2[kt] = *(const v8s*)&w2t[(size_t)(w * 16 + l15) * 128 + kt * 32 + q * 8];
    v4f acc2[4] = {};
#pragma unroll
    for (int kt = 0; kt < 4; kt++)
#pragma unroll
        for (int mt = 0; mt < 4; mt++) {
            v8s a = *(const v8s*)&za[(mt * 16 + l15) * 136 + kt * 32 + q * 8];
            acc2[mt] = MFMA(a, b2[kt], acc2[mt]);
        }

    {
        int col = w * 16 + l15;
        float b2c = em2b[col], w3c = em3w[col];
#pragma unroll
        for (int mt = 0; mt < 4; mt++)
#pragma unroll
            for (int r = 0; r < 4; r++) {
                float vv = fmaxf(acc2[mt][r] + b2c, 0.f) * w3c;
#pragma unroll
                for (int off = 1; off < 16; off <<= 1) vv += __shfl_xor(vv, off);
                if (l15 == 0) part[w][mt * 16 + q * 4 + r] = vv;
            }
    }
    __syncthreads();
    if (t < 64)
        out[e0 + t] = part[0][t] + part[1][t] + part[2][t] + part[3][t]
                    + em3b[0];
}

// ------------------------------------------------------------ launch
extern "C" __attribute__((visibility("default")))
void kernel_launch(void* const* d_in, const int* in_sizes, int n_in,
                   void* d_out, int out_size, void* d_ws, size_t ws_size,
                   hipStream_t stream) {
    float* out = (float*)d_out;

    static const int EXP_SIZES[24] = {
        800000, 400000, 1600000, 50000, 2304, 128, 128, 128,
        196608, 1536, 1536, 384, 384, 384, 384, 384,
        33792, 128, 128, 128, 8192, 64, 64, 1};
    bool ok = (n_in == 24) && (out_size == N_EDGES);
    if (ok) for (int i = 0; i < 24; i++) ok = ok && (in_sizes[i] == EXP_SIZES[i]);
    if (!ok) {
        k_fill<<<(out_size + 255) / 256, 256, 0, stream>>>(out, out_size, 4.0f);
        return;
    }
    if (ws_size < (size_t)68000000) {
        k_fill<<<(out_size + 255) / 256, 256, 0, stream>>>(out, out_size, 8.0f);
        return;
    }

    const int* ei    = (const int*)d_in[1];
    const int* shock = (const int*)d_in[3];

    char* ws = (char*)d_ws;
    unsigned short* h_bf  = (unsigned short*)(ws + 0);          // 12,800,000
    unsigned short* xh    = (unsigned short*)(ws + 12800000);   // 51,200,000
    unsigned short* UV    = xh;   // aliases xh (xh dead before k_uvgemm)
    float* al_s    = (float*)(ws + 64000000);
    float* al_d    = (float*)(ws + 64800000);
    float* down    = (float*)(ws + 65600000);
    int*   deg     = (int*)  (ws + 65800000);
    int*   row_st  = (int*)  (ws + 66000000);
    int*   fill    = (int*)  (ws + 66200064);
    int*   csr_src = (int*)  (ws + 66400064);
    int*   flag    = (int*)  (ws + 67400064);
    unsigned short* gwt = (unsigned short*)(ws + 67400128);     // 393,216
    unsigned short* uvt = (unsigned short*)(ws + 67793344);     // 65,536
    unsigned short* w2t = (unsigned short*)(ws + 67858880);     // 16,384
    float* pool    = (float*)(ws + 67875264);                   // 9,224 f32

    float* cencw = pool + 0;    float* cencb = pool + 2304;
    float* cenlg = pool + 2432; float* cenlb = pool + 2560;
    float* casrc = pool + 2688; float* cadst = pool + 4224;
    float* cbias = pool + 5760; float* cbng  = pool + 6144;
    float* cbnb  = pool + 6528; float* cbnm  = pool + 6912;
    float* cbnv  = pool + 7296; float* cem1b = pool + 7680;
    float* cemlg = pool + 7808; float* cemlb = pool + 7936;
    float* cem2b = pool + 8064; float* cem3w = pool + 8128;
    float* cem3b = pool + 8192;
    float* w1e   = pool + 8200;   // [8][128]

    k_detect<<<1, 64, 0, stream>>>((const unsigned short*)d_in[0], flag);

    PrepArgs pa;
    pa.encw = d_in[4];  pa.encb = d_in[5];  pa.enlg = d_in[6];  pa.enlb = d_in[7];
    pa.gatw = d_in[8];  pa.asrc = d_in[9];  pa.adst = d_in[10]; pa.bias = d_in[11];
    pa.bng  = d_in[12]; pa.bnb  = d_in[13]; pa.bnm  = d_in[14]; pa.bnv  = d_in[15];
    pa.em1w = d_in[16]; pa.em1b = d_in[17]; pa.emlg = d_in[18]; pa.emlb = d_in[19];
    pa.em2w = d_in[20]; pa.em2b = d_in[21]; pa.em3w = d_in[22]; pa.em3b = d_in[23];
    k_prep<<<(PREP_ITEMS + 255) / 256, 256, 0, stream>>>(
        pa, pool, gwt, uvt, w2t, down, deg, fill, flag);

    k_graph<<<(ETOT + 255) / 256, 256, 0, stream>>>(ei, shock, down, deg);
    k_scan<<<1, 1024, 0, stream>>>(deg, row_st);
    k_csr<<<(ETOT + 255) / 256, 256, 0, stream>>>(ei, row_st, fill, csr_src);
    k_encoder<<<N_NODES / 4, 256, 0, stream>>>(
        d_in[0], flag, shock, down, cencw, cencb, cenlg, cenlb, h_bf);
    for (int i = 0; i < 3; i++) {
        k_gemm<<<dim3(782, 4), 256, 0, stream>>>(
            h_bf, gwt + (size_t)i * 65536, casrc + i * 512, cadst + i * 512,
            xh, al_s, al_d);
        k_aggregate<<<N_NODES / 4, 256, 0, stream>>>(
            xh, al_s, al_d, row_st, csr_src,
            cbias + i * 128, cbng + i * 128, cbnb + i * 128,
            cbnm + i * 128, cbnv + i * 128, h_bf, (i < 2) ? 1 : 0);
    }
    k_uvgemm<<<dim3(782, 2), 256, 0, stream>>>(h_bf, uvt, UV);
    k_edgemlp2<<<N_EDGES / 64, 256, 0, stream>>>(
        UV, ei, d_in[2], flag, w1e, cem1b, cemlg, cemlb,
        w2t, cem2b, cem3w, cem3b, out);
}

// Round 12
// 484.842 us; speedup vs baseline: 1.6671x; 1.1797x over previous
//
#include <hip/hip_runtime.h>
#include <hip/hip_bf16.h>

// ShockPropagationGNN — round 11: round-10 structure (best: 572us) with the
// single-block k_scan (91us, uncoalesced 1-CU latency bound) replaced by a
// two-phase multi-block scan (k_scan1: block sums; k_scan2: offsets + scan).

#define N_NODES 50000
#define N_EDGES 200000
#define ETOT    (N_EDGES + N_NODES)
#define HID     128
#define LN_EPS  1e-5f
#define NEG     0.2f
#define NSB     196     // scan blocks: 196*256 = 50176 >= N_NODES

typedef __hip_bfloat16 bf16;
typedef __attribute__((ext_vector_type(8))) short v8s;
typedef __attribute__((ext_vector_type(4))) float v4f;
#define MFMA(a, b, c) __builtin_amdgcn_mfma_f32_16x16x32_bf16(a, b, c, 0, 0, 0)

__device__ __forceinline__ float b2f(unsigned short s) {
    return __uint_as_float(((unsigned int)s) << 16);
}
__device__ __forceinline__ unsigned short f2b(float f) {
    __hip_bfloat16 h = __float2bfloat16(f);
    return *reinterpret_cast<unsigned short*>(&h);
}
__device__ __forceinline__ unsigned int pack2(float a, float b) {
    return (unsigned int)f2b(a) | ((unsigned int)f2b(b) << 16);
}
__device__ __forceinline__ float pread(const void* p, size_t i, int isbf) {
    if (isbf) return b2f(((const unsigned short*)p)[i]);
    return ((const float*)p)[i];
}

__global__ void k_fill(float* out, int n, float v) {
    int i = blockIdx.x * blockDim.x + threadIdx.x;
    if (i < n) out[i] = v;
}

// ------------------------------------------------------------ dtype detect
__global__ void k_detect(const unsigned short* __restrict__ xbuf,
                         int* __restrict__ flag) {
    int sane = 0;
    for (int j = threadIdx.x; j < 4096; j += 64) {
        unsigned short v = xbuf[2 * j];
        int e = (v >> 7) & 0xFF;
        if (v == 0 || (e > 96 && e < 160)) sane++;
    }
    for (int off = 32; off > 0; off >>= 1) sane += __shfl_down(sane, off);
    if (threadIdx.x == 0) flag[0] = (sane * 10 >= 4096 * 9) ? 1 : 0;
}

// ------------------------------------------------------------ prep (fused)
struct PrepArgs {
    const void *encw, *encb, *enlg, *enlb, *gatw, *asrc, *adst, *bias,
               *bng, *bnb, *bnm, *bnv, *em1w, *em1b, *emlg, *emlb,
               *em2w, *em2b, *em3w, *em3b;
};
// zeros | pool | w1e | gwt | uvt | w2t
#define PREP_ITEMS (150000 + 8193 + 1024 + 196608 + 32768 + 8192)
__global__ void k_prep(PrepArgs a, float* __restrict__ pool,
                       unsigned short* __restrict__ gwt,   // [L][n=512][k=128]
                       unsigned short* __restrict__ uvt,   // [n=256][k=128]
                       unsigned short* __restrict__ w2t,   // [n=64][k=128]
                       float* __restrict__ down, int* __restrict__ deg,
                       int* __restrict__ fill, const int* __restrict__ flag) {
    int i = blockIdx.x * 256 + threadIdx.x;
    int bf = flag[0];
    if (i < 150000) {
        int which = i / 50000, idx = i - which * 50000;
        if (which == 0) down[idx] = 0.f;
        else if (which == 1) deg[idx] = 0;
        else fill[idx] = 0;
        return;
    }
    i -= 150000;
    if (i < 8193) {
        const void* s; int off;
        if      (i < 2304) { s = a.encw; off = 0;    }
        else if (i < 2432) { s = a.encb; off = 2304; }
        else if (i < 2560) { s = a.enlg; off = 2432; }
        else if (i < 2688) { s = a.enlb; off = 2560; }
        else if (i < 4224) { s = a.asrc; off = 2688; }
        else if (i < 5760) { s = a.adst; off = 4224; }
        else if (i < 6144) { s = a.bias; off = 5760; }
        else if (i < 6528) { s = a.bng;  off = 6144; }
        else if (i < 6912) { s = a.bnb;  off = 6528; }
        else if (i < 7296) { s = a.bnm;  off = 6912; }
        else if (i < 7680) { s = a.bnv;  off = 7296; }
        else if (i < 7808) { s = a.em1b; off = 7680; }
        else if (i < 7936) { s = a.emlg; off = 7808; }
        else if (i < 8064) { s = a.emlb; off = 7936; }
        else if (i < 8128) { s = a.em2b; off = 8064; }
        else if (i < 8192) { s = a.em3w; off = 8128; }
        else               { s = a.em3b; off = 8192; }
        pool[i] = pread(s, i - off, bf);
        return;
    }
    i -= 8193;
    if (i < 1024) {     // w1e fp32: pool[8200 + k*128+c] = em1_w[256+k][c]
        int k = i >> 7, c = i & 127;
        pool[8200 + i] = pread(a.em1w, (size_t)(256 + k) * 128 + c, bf);
        return;
    }
    i -= 1024;
    if (i < 196608) {   // gwt[L][n][k] = gat_w[L][k][n]
        int L = i >> 16, rem = i & 65535, n = rem >> 7, k = rem & 127;
        gwt[i] = f2b(pread(a.gatw, (size_t)L * 65536 + (size_t)k * 512 + n, bf));
        return;
    }
    i -= 196608;
    if (i < 32768) {    // uvt[n][k]: n<128 -> em1_w[k][n]; else em1_w[128+k][n-128]
        int n = i >> 7, k = i & 127;
        float v = (n < 128) ? pread(a.em1w, (size_t)k * 128 + n, bf)
                            : pread(a.em1w, (size_t)(128 + k) * 128 + (n - 128), bf);
        uvt[i] = f2b(v);
        return;
    }
    i -= 32768;
    if (i < 8192) {     // w2t[n][k] = em2_w[k][n]
        int n = i >> 7, k = i & 127;
        w2t[i] = f2b(pread(a.em2w, (size_t)k * 64 + n, bf));
    }
}

// ------------------------------------------------------------ graph build
__global__ void k_graph(const int* __restrict__ ei, const int* __restrict__ shock,
                        float* __restrict__ down, int* __restrict__ deg) {
    int e = blockIdx.x * blockDim.x + threadIdx.x;
    if (e < ETOT) {
        int d = (e < N_EDGES) ? ei[N_EDGES + e] : (e - N_EDGES);
        atomicAdd(&deg[d], 1);
        if (e < N_EDGES && shock[ei[e]] != 0) down[d] = 1.f;
    }
}

// ------------------------------------------------------------ scan (2-phase)
__global__ __launch_bounds__(256) void k_scan1(
        const int* __restrict__ deg, int* __restrict__ bsum) {
    __shared__ int red[4];
    int b = blockIdx.x, t = threadIdx.x, lane = t & 63, w = t >> 6;
    int idx = b * 256 + t;
    int v = (idx < N_NODES) ? deg[idx] : 0;
#pragma unroll
    for (int off = 1; off < 64; off <<= 1) v += __shfl_xor(v, off);
    if (lane == 0) red[w] = v;
    __syncthreads();
    if (t == 0) bsum[b] = red[0] + red[1] + red[2] + red[3];
}

__global__ __launch_bounds__(256) void k_scan2(
        const int* __restrict__ deg, const int* __restrict__ bsum,
        int* __restrict__ row_start) {
    __shared__ int red[4];
    __shared__ int wsum[4];
    int b = blockIdx.x, t = threadIdx.x, lane = t & 63, w = t >> 6;
    // block offset = sum of bsum[0..b)  (b < 256, one block reduce)
    int pv = (t < b) ? bsum[t] : 0;
    int sm = pv;
#pragma unroll
    for (int off = 1; off < 64; off <<= 1) sm += __shfl_xor(sm, off);
    if (lane == 0) red[w] = sm;
    // per-element intra-block exclusive scan
    int idx = b * 256 + t;
    int v = (idx < N_NODES) ? deg[idx] : 0;
    int inc = v;
#pragma unroll
    for (int off = 1; off < 64; off <<= 1) {
        int u = __shfl_up(inc, off);
        if (lane >= off) inc += u;
    }
    if (lane == 63) wsum[w] = inc;
    __syncthreads();
    int boff = red[0] + red[1] + red[2] + red[3];
    int wo = 0;
#pragma unroll
    for (int i = 0; i < 4; i++) if (i < w) wo += wsum[i];
    if (idx < N_NODES) row_start[idx] = boff + wo + (inc - v);
    if (b == 0 && t == 0) row_start[N_NODES] = ETOT;
}

__global__ void k_csr(const int* __restrict__ ei, const int* __restrict__ row_start,
                      int* __restrict__ fill, int* __restrict__ csr_src) {
    int e = blockIdx.x * blockDim.x + threadIdx.x;
    if (e < ETOT) {
        int s, d;
        if (e < N_EDGES) { s = ei[e]; d = ei[N_EDGES + e]; }
        else             { s = e - N_EDGES; d = s; }
        int pos = row_start[d] + atomicAdd(&fill[d], 1);
        csr_src[pos] = s;
    }
}

// ------------------------------------------------------------ encoder -> h bf16
__global__ __launch_bounds__(256) void k_encoder(
        const void* __restrict__ xraw, const int* __restrict__ flag,
        const int* __restrict__ shock, const float* __restrict__ down,
        const float* __restrict__ enc_w, const float* __restrict__ enc_b,
        const float* __restrict__ ln_g, const float* __restrict__ ln_b,
        unsigned short* __restrict__ h) {
    __shared__ float sw[2304];
    __shared__ float sp[384];
    int t = threadIdx.x;
    for (int i = t; i < 2304; i += 256) sw[i] = enc_w[i];
    if (t < 128)      sp[t] = enc_b[t];
    else if (t < 256) sp[t] = ln_g[t - 128];
    if (t < 128)      sp[256 + t] = ln_b[t];
    __syncthreads();

    int w = t >> 6, l = t & 63;
    int n = blockIdx.x * 4 + w;
    int bf = flag[0];
    int c0 = 2 * l, c1 = c0 + 1;

    float xv = (l < 16) ? pread(xraw, (size_t)n * 16 + l, bf) : 0.f;
    float xs = (float)shock[n];
    float xd = down[n];

    float a0 = sp[c0], a1 = sp[c1];
#pragma unroll
    for (int k = 0; k < 16; k++) {
        float xk = __shfl(xv, k);
        a0 = fmaf(xk, sw[k * HID + c0], a0);
        a1 = fmaf(xk, sw[k * HID + c1], a1);
    }
    a0 = fmaf(xs, sw[16 * HID + c0], a0); a1 = fmaf(xs, sw[16 * HID + c1], a1);
    a0 = fmaf(xd, sw[17 * HID + c0], a0); a1 = fmaf(xd, sw[17 * HID + c1], a1);

    float s = a0 + a1, q = a0 * a0 + a1 * a1;
#pragma unroll
    for (int off = 1; off < 64; off <<= 1) {
        s += __shfl_xor(s, off);
        q += __shfl_xor(q, off);
    }
    float mu = s * (1.f / 128.f);
    float var = q * (1.f / 128.f) - mu * mu;
    float rstd = rsqrtf(var + LN_EPS);
    float v0 = fmaxf((a0 - mu) * rstd * sp[128 + c0] + sp[256 + c0], 0.f);
    float v1 = fmaxf((a1 - mu) * rstd * sp[128 + c1] + sp[256 + c1], 0.f);
    *(unsigned int*)&h[(size_t)n * HID + c0] = pack2(v0, v1);
}

// ------------------------------------------------------------ GAT GEMM + logits
__global__ __launch_bounds__(256, 4) void k_gemm(
        const unsigned short* __restrict__ A, const unsigned short* __restrict__ Wt,
        const float* __restrict__ asrc, const float* __restrict__ adst,
        unsigned short* __restrict__ C,
        float* __restrict__ al_s, float* __restrict__ al_d) {
    __shared__ __align__(16) unsigned short As[64 * 136];
    __shared__ float alp[64][4][2];
    int t = threadIdx.x;
    int lane = t & 63, w = t >> 6, l15 = lane & 15, q = lane >> 4;
    int m0 = blockIdx.x * 64, n0 = blockIdx.y * 128, head = blockIdx.y;
    int c0 = n0 + w * 32 + 2 * l15, c1 = c0 + 1;

    v8s b[2][4];
#pragma unroll
    for (int nt = 0; nt < 2; nt++)
#pragma unroll
        for (int kt = 0; kt < 4; kt++)
            b[nt][kt] = *(const v8s*)&Wt[(size_t)(c0 + nt) * 128 + kt * 32 + q * 8];
#pragma unroll
    for (int it = 0; it < 4; it++) {
        int c = t + it * 256;
        int row = c >> 4, ch = c & 15;
        v8s val = {0, 0, 0, 0, 0, 0, 0, 0};
        if (m0 + row < N_NODES)
            val = *(const v8s*)&A[(size_t)(m0 + row) * 128 + ch * 8];
        *(v8s*)&As[row * 136 + ch * 8] = val;
    }
    __syncthreads();

    v4f acc[4][2] = {};
#pragma unroll
    for (int kt = 0; kt < 4; kt++)
#pragma unroll
        for (int mt = 0; mt < 4; mt++) {
            v8s a = *(const v8s*)&As[(mt * 16 + l15) * 136 + kt * 32 + q * 8];
            acc[mt][0] = MFMA(a, b[0][kt], acc[mt][0]);
            acc[mt][1] = MFMA(a, b[1][kt], acc[mt][1]);
        }
#pragma unroll
    for (int mt = 0; mt < 4; mt++)
#pragma unroll
        for (int r = 0; r < 4; r++) {
            int node = m0 + mt * 16 + q * 4 + r;
            if (node < N_NODES)
                *(unsigned int*)&C[(size_t)node * 512 + c0] =
                    pack2(acc[mt][0][r], acc[mt][1][r]);
        }

    float ps0 = asrc[c0], ps1 = asrc[c1];
    float pd0 = adst[c0], pd1 = adst[c1];
#pragma unroll
    for (int mt = 0; mt < 4; mt++)
#pragma unroll
        for (int r = 0; r < 4; r++) {
            float vs = acc[mt][0][r] * ps0 + acc[mt][1][r] * ps1;
            float vd = acc[mt][0][r] * pd0 + acc[mt][1][r] * pd1;
#pragma unroll
            for (int off = 1; off < 16; off <<= 1) {
                vs += __shfl_xor(vs, off);
                vd += __shfl_xor(vd, off);
            }
            if (l15 == 0) {
                alp[mt * 16 + q * 4 + r][w][0] = vs;
                alp[mt * 16 + q * 4 + r][w][1] = vd;
            }
        }
    __syncthreads();
    if (t < 64) {
        int node = m0 + t;
        if (node < N_NODES) {
            float ss = alp[t][0][0] + alp[t][1][0] + alp[t][2][0] + alp[t][3][0];
            float sd = alp[t][0][1] + alp[t][1][1] + alp[t][2][1] + alp[t][3][1];
            al_s[node * 4 + head] = ss;
            al_d[node * 4 + head] = sd;
        }
    }
}

// ------------------------------------------------------------ aggregation
__global__ __launch_bounds__(256) void k_aggregate(
        const unsigned short* __restrict__ xh, const float* __restrict__ al_src,
        const float* __restrict__ al_dst,
        const int* __restrict__ row_start, const int* __restrict__ csr_src,
        const float* __restrict__ bias,
        const float* __restrict__ bn_g, const float* __restrict__ bn_b,
        const float* __restrict__ bn_m, const float* __restrict__ bn_v,
        unsigned short* __restrict__ h, int relu_flag) {
    int w = threadIdx.x >> 6, l = threadIdx.x & 63;
    int n = blockIdx.x * 4 + w;
    int hh = l >> 4, c8 = l & 15;
    int r0 = row_start[n], r1 = row_start[n + 1];
    float ad = al_dst[n * 4 + hh];
    float sh = 0.f;
    float acc[8] = {};
    for (int j = r0; j < r1; j++) {
        int s = csr_src[j];
        float a = al_src[s * 4 + hh] + ad;
        a = (a >= 0.f) ? a : NEG * a;
        float we = __expf(a);
        sh += we;
        v8s row = *(const v8s*)&xh[(size_t)s * 512 + l * 8];
#pragma unroll
        for (int i = 0; i < 8; i++)
            acc[i] = fmaf(we, b2f((unsigned short)row[i]), acc[i]);
    }
    float inv = 1.f / (sh + 1e-16f);
#pragma unroll
    for (int i = 0; i < 8; i++) {
        acc[i] *= inv;
        acc[i] += __shfl_xor(acc[i], 16);
        acc[i] += __shfl_xor(acc[i], 32);
    }
    if (hh == 0) {
        int cbase = c8 * 8;
        short o[8];
#pragma unroll
        for (int i = 0; i < 8; i++) {
            int c = cbase + i;
            float v = 0.25f * acc[i] + bias[c];
            v = (v - bn_m[c]) * rsqrtf(bn_v[c] + LN_EPS) * bn_g[c] + bn_b[c];
            if (relu_flag) v = fmaxf(v, 0.f);
            o[i] = (short)f2b(v);
        }
        *(v8s*)&h[(size_t)n * 128 + cbase] = *(const v8s*)o;
    }
}

// ------------------------------------------------------------ UV GEMM
__global__ __launch_bounds__(256, 4) void k_uvgemm(
        const unsigned short* __restrict__ A, const unsigned short* __restrict__ Wt,
        unsigned short* __restrict__ UV) {
    __shared__ __align__(16) unsigned short As[64 * 136];
    int t = threadIdx.x;
    int lane = t & 63, w = t >> 6, l15 = lane & 15, q = lane >> 4;
    int m0 = blockIdx.x * 64, n0 = blockIdx.y * 128;
    int c0 = n0 + w * 32 + 2 * l15;

    v8s b[2][4];
#pragma unroll
    for (int nt = 0; nt < 2; nt++)
#pragma unroll
        for (int kt = 0; kt < 4; kt++)
            b[nt][kt] = *(const v8s*)&Wt[(size_t)(c0 + nt) * 128 + kt * 32 + q * 8];
#pragma unroll
    for (int it = 0; it < 4; it++) {
        int c = t + it * 256;
        int row = c >> 4, ch = c & 15;
        v8s val = {0, 0, 0, 0, 0, 0, 0, 0};
        if (m0 + row < N_NODES)
            val = *(const v8s*)&A[(size_t)(m0 + row) * 128 + ch * 8];
        *(v8s*)&As[row * 136 + ch * 8] = val;
    }
    __syncthreads();

    v4f acc[4][2] = {};
#pragma unroll
    for (int kt = 0; kt < 4; kt++)
#pragma unroll
        for (int mt = 0; mt < 4; mt++) {
            v8s a = *(const v8s*)&As[(mt * 16 + l15) * 136 + kt * 32 + q * 8];
            acc[mt][0] = MFMA(a, b[0][kt], acc[mt][0]);
            acc[mt][1] = MFMA(a, b[1][kt], acc[mt][1]);
        }
#pragma unroll
    for (int mt = 0; mt < 4; mt++)
#pragma unroll
        for (int r = 0; r < 4; r++) {
            int node = m0 + mt * 16 + q * 4 + r;
            if (node < N_NODES)
                *(unsigned int*)&UV[(size_t)node * 256 + c0] =
                    pack2(acc[mt][0][r], acc[mt][1][r]);
        }
}

// ------------------------------------------------------------ edge MLP v2
__global__ __launch_bounds__(256) void k_edgemlp2(
        const unsigned short* __restrict__ UV, const int* __restrict__ ei,
        const void* __restrict__ eraw, const int* __restrict__ flag,
        const float* __restrict__ w1e, const float* __restrict__ em1b,
        const float* __restrict__ lng, const float* __restrict__ lnb,
        const unsigned short* __restrict__ w2t, const float* __restrict__ em2b,
        const float* __restrict__ em3w, const float* __restrict__ em3b,
        float* __restrict__ out) {
    __shared__ __align__(16) unsigned short za[64 * 136];
    __shared__ float w1e_s[1024];
    __shared__ unsigned short ea_s[64 * 8];
    __shared__ int idx_s[128];
    __shared__ float part[4][64];

    int t = threadIdx.x;
    int lane = t & 63, w = t >> 6, l15 = lane & 15, q = lane >> 4;
    int e0 = blockIdx.x * 64;
    int bf = flag[0];

    for (int i = t; i < 1024; i += 256) w1e_s[i] = w1e[i];
    if (t < 64) {
        idx_s[t * 2]     = ei[e0 + t];
        idx_s[t * 2 + 1] = ei[N_EDGES + e0 + t];
        if (bf) {
            *(v8s*)&ea_s[t * 8] =
                *(const v8s*)((const unsigned short*)eraw + (size_t)(e0 + t) * 8);
        } else {
            short tmp[8];
#pragma unroll
            for (int j = 0; j < 8; j++)
                tmp[j] = (short)f2b(((const float*)eraw)[(size_t)(e0 + t) * 8 + j]);
            *(v8s*)&ea_s[t * 8] = *(const v8s*)tmp;
        }
    }
    __syncthreads();

    int c0 = 2 * lane, c1 = c0 + 1;
    float bc0 = em1b[c0], bc1 = em1b[c1];
    float lg0 = lng[c0], lg1 = lng[c1], lb0 = lnb[c0], lb1 = lnb[c1];

    int el0 = w * 16;
    unsigned int u = *(const unsigned int*)&UV[(size_t)idx_s[el0 * 2] * 256 + c0];
    unsigned int v = *(const unsigned int*)&UV[(size_t)idx_s[el0 * 2 + 1] * 256 + 128 + c0];
#pragma unroll 1
    for (int i = 0; i < 16; i++) {
        int el = w * 16 + i;
        unsigned int uc = u, vc = v;
        if (i < 15) {
            int el2 = el + 1;
            u = *(const unsigned int*)&UV[(size_t)idx_s[el2 * 2] * 256 + c0];
            v = *(const unsigned int*)&UV[(size_t)idx_s[el2 * 2 + 1] * 256 + 128 + c0];
        }
        float e0t = 0.f, e1t = 0.f;
#pragma unroll
        for (int k = 0; k < 8; k++) {
            float eak = b2f(ea_s[el * 8 + k]);
            e0t = fmaf(eak, w1e_s[k * 128 + c0], e0t);
            e1t = fmaf(eak, w1e_s[k * 128 + c1], e1t);
        }
        float z0 = b2f(uc & 0xffff) + b2f(vc & 0xffff) + e0t + bc0;
        float z1 = b2f(uc >> 16) + b2f(vc >> 16) + e1t + bc1;
        float s = z0 + z1, qq = z0 * z0 + z1 * z1;
#pragma unroll
        for (int off = 1; off < 64; off <<= 1) {
            s  += __shfl_xor(s, off);
            qq += __shfl_xor(qq, off);
        }
        float mu = s * (1.f / 128.f);
        float var = qq * (1.f / 128.f) - mu * mu;
        float rstd = rsqrtf(var + LN_EPS);
        float y0 = fmaxf((z0 - mu) * rstd * lg0 + lb0, 0.f);
        float y1 = fmaxf((z1 - mu) * rstd * lg1 + lb1, 0.f);
        *(unsigned int*)&za[el * 136 + c0] = pack2(y0, y1);
    }
    __syncthreads();

    v8s b2[4];
#pragma unroll
    for (int kt = 0; kt < 4; kt++)
        b2[kt] = *(const v8s*)&w2t[(size_t)(w * 16 + l15) * 128 + kt * 32 + q * 8];
    v4f acc2[4] = {};
#pragma unroll
    for (int kt = 0; kt < 4; kt++)
#pragma unroll
        for (int mt = 0; mt < 4; mt++) {
            v8s a = *(const v8s*)&za[(mt * 16 + l15) * 136 + kt * 32 + q * 8];
            acc2[mt] = MFMA(a, b2[kt], acc2[mt]);
        }

    {
        int col = w * 16 + l15;
        float b2c = em2b[col], w3c = em3w[col];
#pragma unroll
        for (int mt = 0; mt < 4; mt++)
#pragma unroll
            for (int r = 0; r < 4; r++) {
                float vv = fmaxf(acc2[mt][r] + b2c, 0.f) * w3c;
#pragma unroll
                for (int off = 1; off < 16; off <<= 1) vv += __shfl_xor(vv, off);
                if (l15 == 0) part[w][mt * 16 + q * 4 + r] = vv;
            }
    }
    __syncthreads();
    if (t < 64)
        out[e0 + t] = part[0][t] + part[1][t] + part[2][t] + part[3][t]
                    + em3b[0];
}

// ------------------------------------------------------------ launch
extern "C" __attribute__((visibility("default")))
void kernel_launch(void* const* d_in, const int* in_sizes, int n_in,
                   void* d_out, int out_size, void* d_ws, size_t ws_size,
                   hipStream_t stream) {
    float* out = (float*)d_out;

    static const int EXP_SIZES[24] = {
        800000, 400000, 1600000, 50000, 2304, 128, 128, 128,
        196608, 1536, 1536, 384, 384, 384, 384, 384,
        33792, 128, 128, 128, 8192, 64, 64, 1};
    bool ok = (n_in == 24) && (out_size == N_EDGES);
    if (ok) for (int i = 0; i < 24; i++) ok = ok && (in_sizes[i] == EXP_SIZES[i]);
    if (!ok) {
        k_fill<<<(out_size + 255) / 256, 256, 0, stream>>>(out, out_size, 4.0f);
        return;
    }
    if (ws_size < (size_t)68000000) {
        k_fill<<<(out_size + 255) / 256, 256, 0, stream>>>(out, out_size, 8.0f);
        return;
    }

    const int* ei    = (const int*)d_in[1];
    const int* shock = (const int*)d_in[3];

    char* ws = (char*)d_ws;
    unsigned short* h_bf  = (unsigned short*)(ws + 0);          // 12,800,000
    unsigned short* xh    = (unsigned short*)(ws + 12800000);   // 51,200,000
    unsigned short* UV    = xh;   // aliases xh (xh dead before k_uvgemm)
    float* al_s    = (float*)(ws + 64000000);
    float* al_d    = (float*)(ws + 64800000);
    float* down    = (float*)(ws + 65600000);
    int*   deg     = (int*)  (ws + 65800000);
    int*   row_st  = (int*)  (ws + 66000000);
    int*   fill    = (int*)  (ws + 66200064);
    int*   csr_src = (int*)  (ws + 66400064);
    int*   flag    = (int*)  (ws + 67400064);
    unsigned short* gwt = (unsigned short*)(ws + 67400128);     // 393,216
    unsigned short* uvt = (unsigned short*)(ws + 67793344);     // 65,536
    unsigned short* w2t = (unsigned short*)(ws + 67858880);     // 16,384
    float* pool    = (float*)(ws + 67875264);                   // 9,224 f32
    int*   bsum    = (int*)  (ws + 67912160);                   // 784 B

    float* cencw = pool + 0;    float* cencb = pool + 2304;
    float* cenlg = pool + 2432; float* cenlb = pool + 2560;
    float* casrc = pool + 2688; float* cadst = pool + 4224;
    float* cbias = pool + 5760; float* cbng  = pool + 6144;
    float* cbnb  = pool + 6528; float* cbnm  = pool + 6912;
    float* cbnv  = pool + 7296; float* cem1b = pool + 7680;
    float* cemlg = pool + 7808; float* cemlb = pool + 7936;
    float* cem2b = pool + 8064; float* cem3w = pool + 8128;
    float* cem3b = pool + 8192;
    float* w1e   = pool + 8200;   // [8][128]

    k_detect<<<1, 64, 0, stream>>>((const unsigned short*)d_in[0], flag);

    PrepArgs pa;
    pa.encw = d_in[4];  pa.encb = d_in[5];  pa.enlg = d_in[6];  pa.enlb = d_in[7];
    pa.gatw = d_in[8];  pa.asrc = d_in[9];  pa.adst = d_in[10]; pa.bias = d_in[11];
    pa.bng  = d_in[12]; pa.bnb  = d_in[13]; pa.bnm  = d_in[14]; pa.bnv  = d_in[15];
    pa.em1w = d_in[16]; pa.em1b = d_in[17]; pa.emlg = d_in[18]; pa.emlb = d_in[19];
    pa.em2w = d_in[20]; pa.em2b = d_in[21]; pa.em3w = d_in[22]; pa.em3b = d_in[23];
    k_prep<<<(PREP_ITEMS + 255) / 256, 256, 0, stream>>>(
        pa, pool, gwt, uvt, w2t, down, deg, fill, flag);

    k_graph<<<(ETOT + 255) / 256, 256, 0, stream>>>(ei, shock, down, deg);
    k_scan1<<<NSB, 256, 0, stream>>>(deg, bsum);
    k_scan2<<<NSB, 256, 0, stream>>>(deg, bsum, row_st);
    k_csr<<<(ETOT + 255) / 256, 256, 0, stream>>>(ei, row_st, fill, csr_src);
    k_encoder<<<N_NODES / 4, 256, 0, stream>>>(
        d_in[0], flag, shock, down, cencw, cencb, cenlg, cenlb, h_bf);
    for (int i = 0; i < 3; i++) {
        k_gemm<<<dim3(782, 4), 256, 0, stream>>>(
            h_bf, gwt + (size_t)i * 65536, casrc + i * 512, cadst + i * 512,
            xh, al_s, al_d);
        k_aggregate<<<N_NODES / 4, 256, 0, stream>>>(
            xh, al_s, al_d, row_st, csr_src,
            cbias + i * 128, cbng + i * 128, cbnb + i * 128,
            cbnm + i * 128, cbnv + i * 128, h_bf, (i < 2) ? 1 : 0);
    }
    k_uvgemm<<<dim3(782, 2), 256, 0, stream>>>(h_bf, uvt, UV);
    k_edgemlp2<<<N_EDGES / 64, 256, 0, stream>>>(
        UV, ei, d_in[2], flag, w1e, cem1b, cemlg, cemlb,
        w2t, cem2b, cem3w, cem3b, out);
}

// Round 13
// 466.989 us; speedup vs baseline: 1.7308x; 1.0382x over previous
//
#include <hip/hip_runtime.h>
#include <hip/hip_bf16.h>

// ShockPropagationGNN — round 12 (base: round 11, 484.8us).
// - k_edgemlp3: 16-lanes-per-edge (4 parallel edges/wave, 4 iters vs 16;
//   LN shfl chain 6 steps/64 lanes -> 4 steps/16 lanes; ea@W1e in registers).
// - k_aggregate: branch-free prefetch of next (src, al, xh-row).

#define N_NODES 50000
#define N_EDGES 200000
#define ETOT    (N_EDGES + N_NODES)
#define HID     128
#define LN_EPS  1e-5f
#define NEG     0.2f
#define NSB     196

typedef __hip_bfloat16 bf16;
typedef __attribute__((ext_vector_type(8))) short v8s;
typedef __attribute__((ext_vector_type(4))) float v4f;
#define MFMA(a, b, c) __builtin_amdgcn_mfma_f32_16x16x32_bf16(a, b, c, 0, 0, 0)

__device__ __forceinline__ float b2f(unsigned short s) {
    return __uint_as_float(((unsigned int)s) << 16);
}
__device__ __forceinline__ unsigned short f2b(float f) {
    __hip_bfloat16 h = __float2bfloat16(f);
    return *reinterpret_cast<unsigned short*>(&h);
}
__device__ __forceinline__ unsigned int pack2(float a, float b) {
    return (unsigned int)f2b(a) | ((unsigned int)f2b(b) << 16);
}
__device__ __forceinline__ float pread(const void* p, size_t i, int isbf) {
    if (isbf) return b2f(((const unsigned short*)p)[i]);
    return ((const float*)p)[i];
}

__global__ void k_fill(float* out, int n, float v) {
    int i = blockIdx.x * blockDim.x + threadIdx.x;
    if (i < n) out[i] = v;
}

// ------------------------------------------------------------ dtype detect
__global__ void k_detect(const unsigned short* __restrict__ xbuf,
                         int* __restrict__ flag) {
    int sane = 0;
    for (int j = threadIdx.x; j < 4096; j += 64) {
        unsigned short v = xbuf[2 * j];
        int e = (v >> 7) & 0xFF;
        if (v == 0 || (e > 96 && e < 160)) sane++;
    }
    for (int off = 32; off > 0; off >>= 1) sane += __shfl_down(sane, off);
    if (threadIdx.x == 0) flag[0] = (sane * 10 >= 4096 * 9) ? 1 : 0;
}

// ------------------------------------------------------------ prep (fused)
struct PrepArgs {
    const void *encw, *encb, *enlg, *enlb, *gatw, *asrc, *adst, *bias,
               *bng, *bnb, *bnm, *bnv, *em1w, *em1b, *emlg, *emlb,
               *em2w, *em2b, *em3w, *em3b;
};
// zeros | pool | w1et | gwt | uvt | w2t
#define PREP_ITEMS (150000 + 8193 + 1024 + 196608 + 32768 + 8192)
__global__ void k_prep(PrepArgs a, float* __restrict__ pool,
                       unsigned short* __restrict__ gwt,   // [L][n=512][k=128]
                       unsigned short* __restrict__ uvt,   // [n=256][k=128]
                       unsigned short* __restrict__ w2t,   // [n=64][k=128]
                       unsigned short* __restrict__ w1et,  // [c=128][k=8] bf16
                       float* __restrict__ down, int* __restrict__ deg,
                       int* __restrict__ fill, const int* __restrict__ flag) {
    int i = blockIdx.x * 256 + threadIdx.x;
    int bf = flag[0];
    if (i < 150000) {
        int which = i / 50000, idx = i - which * 50000;
        if (which == 0) down[idx] = 0.f;
        else if (which == 1) deg[idx] = 0;
        else fill[idx] = 0;
        return;
    }
    i -= 150000;
    if (i < 8193) {
        const void* s; int off;
        if      (i < 2304) { s = a.encw; off = 0;    }
        else if (i < 2432) { s = a.encb; off = 2304; }
        else if (i < 2560) { s = a.enlg; off = 2432; }
        else if (i < 2688) { s = a.enlb; off = 2560; }
        else if (i < 4224) { s = a.asrc; off = 2688; }
        else if (i < 5760) { s = a.adst; off = 4224; }
        else if (i < 6144) { s = a.bias; off = 5760; }
        else if (i < 6528) { s = a.bng;  off = 6144; }
        else if (i < 6912) { s = a.bnb;  off = 6528; }
        else if (i < 7296) { s = a.bnm;  off = 6912; }
        else if (i < 7680) { s = a.bnv;  off = 7296; }
        else if (i < 7808) { s = a.em1b; off = 7680; }
        else if (i < 7936) { s = a.emlg; off = 7808; }
        else if (i < 8064) { s = a.emlb; off = 7936; }
        else if (i < 8128) { s = a.em2b; off = 8064; }
        else if (i < 8192) { s = a.em3w; off = 8128; }
        else               { s = a.em3b; off = 8192; }
        pool[i] = pread(s, i - off, bf);
        return;
    }
    i -= 8193;
    if (i < 1024) {     // w1et[c][k] = em1_w[256+k][c]
        int c = i >> 3, k = i & 7;
        w1et[c * 8 + k] = f2b(pread(a.em1w, (size_t)(256 + k) * 128 + c, bf));
        return;
    }
    i -= 1024;
    if (i < 196608) {   // gwt[L][n][k] = gat_w[L][k][n]
        int L = i >> 16, rem = i & 65535, n = rem >> 7, k = rem & 127;
        gwt[i] = f2b(pread(a.gatw, (size_t)L * 65536 + (size_t)k * 512 + n, bf));
        return;
    }
    i -= 196608;
    if (i < 32768) {    // uvt[n][k]: n<128 -> em1_w[k][n]; else em1_w[128+k][n-128]
        int n = i >> 7, k = i & 127;
        float v = (n < 128) ? pread(a.em1w, (size_t)k * 128 + n, bf)
                            : pread(a.em1w, (size_t)(128 + k) * 128 + (n - 128), bf);
        uvt[i] = f2b(v);
        return;
    }
    i -= 32768;
    if (i < 8192) {     // w2t[n][k] = em2_w[k][n]
        int n = i >> 7, k = i & 127;
        w2t[i] = f2b(pread(a.em2w, (size_t)k * 64 + n, bf));
    }
}

// ------------------------------------------------------------ graph build
__global__ void k_graph(const int* __restrict__ ei, const int* __restrict__ shock,
                        float* __restrict__ down, int* __restrict__ deg) {
    int e = blockIdx.x * blockDim.x + threadIdx.x;
    if (e < ETOT) {
        int d = (e < N_EDGES) ? ei[N_EDGES + e] : (e - N_EDGES);
        atomicAdd(&deg[d], 1);
        if (e < N_EDGES && shock[ei[e]] != 0) down[d] = 1.f;
    }
}

// ------------------------------------------------------------ scan (2-phase)
__global__ __launch_bounds__(256) void k_scan1(
        const int* __restrict__ deg, int* __restrict__ bsum) {
    __shared__ int red[4];
    int b = blockIdx.x, t = threadIdx.x, lane = t & 63, w = t >> 6;
    int idx = b * 256 + t;
    int v = (idx < N_NODES) ? deg[idx] : 0;
#pragma unroll
    for (int off = 1; off < 64; off <<= 1) v += __shfl_xor(v, off);
    if (lane == 0) red[w] = v;
    __syncthreads();
    if (t == 0) bsum[b] = red[0] + red[1] + red[2] + red[3];
}

__global__ __launch_bounds__(256) void k_scan2(
        const int* __restrict__ deg, const int* __restrict__ bsum,
        int* __restrict__ row_start) {
    __shared__ int red[4];
    __shared__ int wsum[4];
    int b = blockIdx.x, t = threadIdx.x, lane = t & 63, w = t >> 6;
    int pv = (t < b) ? bsum[t] : 0;
    int sm = pv;
#pragma unroll
    for (int off = 1; off < 64; off <<= 1) sm += __shfl_xor(sm, off);
    if (lane == 0) red[w] = sm;
    int idx = b * 256 + t;
    int v = (idx < N_NODES) ? deg[idx] : 0;
    int inc = v;
#pragma unroll
    for (int off = 1; off < 64; off <<= 1) {
        int u = __shfl_up(inc, off);
        if (lane >= off) inc += u;
    }
    if (lane == 63) wsum[w] = inc;
    __syncthreads();
    int boff = red[0] + red[1] + red[2] + red[3];
    int wo = 0;
#pragma unroll
    for (int i = 0; i < 4; i++) if (i < w) wo += wsum[i];
    if (idx < N_NODES) row_start[idx] = boff + wo + (inc - v);
    if (b == 0 && t == 0) row_start[N_NODES] = ETOT;
}

__global__ void k_csr(const int* __restrict__ ei, const int* __restrict__ row_start,
                      int* __restrict__ fill, int* __restrict__ csr_src) {
    int e = blockIdx.x * blockDim.x + threadIdx.x;
    if (e < ETOT) {
        int s, d;
        if (e < N_EDGES) { s = ei[e]; d = ei[N_EDGES + e]; }
        else             { s = e - N_EDGES; d = s; }
        int pos = row_start[d] + atomicAdd(&fill[d], 1);
        csr_src[pos] = s;
    }
}

// ------------------------------------------------------------ encoder -> h bf16
__global__ __launch_bounds__(256) void k_encoder(
        const void* __restrict__ xraw, const int* __restrict__ flag,
        const int* __restrict__ shock, const float* __restrict__ down,
        const float* __restrict__ enc_w, const float* __restrict__ enc_b,
        const float* __restrict__ ln_g, const float* __restrict__ ln_b,
        unsigned short* __restrict__ h) {
    __shared__ float sw[2304];
    __shared__ float sp[384];
    int t = threadIdx.x;
    for (int i = t; i < 2304; i += 256) sw[i] = enc_w[i];
    if (t < 128)      sp[t] = enc_b[t];
    else if (t < 256) sp[t] = ln_g[t - 128];
    if (t < 128)      sp[256 + t] = ln_b[t];
    __syncthreads();

    int w = t >> 6, l = t & 63;
    int n = blockIdx.x * 4 + w;
    int bf = flag[0];
    int c0 = 2 * l, c1 = c0 + 1;

    float xv = (l < 16) ? pread(xraw, (size_t)n * 16 + l, bf) : 0.f;
    float xs = (float)shock[n];
    float xd = down[n];

    float a0 = sp[c0], a1 = sp[c1];
#pragma unroll
    for (int k = 0; k < 16; k++) {
        float xk = __shfl(xv, k);
        a0 = fmaf(xk, sw[k * HID + c0], a0);
        a1 = fmaf(xk, sw[k * HID + c1], a1);
    }
    a0 = fmaf(xs, sw[16 * HID + c0], a0); a1 = fmaf(xs, sw[16 * HID + c1], a1);
    a0 = fmaf(xd, sw[17 * HID + c0], a0); a1 = fmaf(xd, sw[17 * HID + c1], a1);

    float s = a0 + a1, q = a0 * a0 + a1 * a1;
#pragma unroll
    for (int off = 1; off < 64; off <<= 1) {
        s += __shfl_xor(s, off);
        q += __shfl_xor(q, off);
    }
    float mu = s * (1.f / 128.f);
    float var = q * (1.f / 128.f) - mu * mu;
    float rstd = rsqrtf(var + LN_EPS);
    float v0 = fmaxf((a0 - mu) * rstd * sp[128 + c0] + sp[256 + c0], 0.f);
    float v1 = fmaxf((a1 - mu) * rstd * sp[128 + c1] + sp[256 + c1], 0.f);
    *(unsigned int*)&h[(size_t)n * HID + c0] = pack2(v0, v1);
}

// ------------------------------------------------------------ GAT GEMM + logits
__global__ __launch_bounds__(256, 4) void k_gemm(
        const unsigned short* __restrict__ A, const unsigned short* __restrict__ Wt,
        const float* __restrict__ asrc, const float* __restrict__ adst,
        unsigned short* __restrict__ C,
        float* __restrict__ al_s, float* __restrict__ al_d) {
    __shared__ __align__(16) unsigned short As[64 * 136];
    __shared__ float alp[64][4][2];
    int t = threadIdx.x;
    int lane = t & 63, w = t >> 6, l15 = lane & 15, q = lane >> 4;
    int m0 = blockIdx.x * 64, n0 = blockIdx.y * 128, head = blockIdx.y;
    int c0 = n0 + w * 32 + 2 * l15, c1 = c0 + 1;

    v8s b[2][4];
#pragma unroll
    for (int nt = 0; nt < 2; nt++)
#pragma unroll
        for (int kt = 0; kt < 4; kt++)
            b[nt][kt] = *(const v8s*)&Wt[(size_t)(c0 + nt) * 128 + kt * 32 + q * 8];
#pragma unroll
    for (int it = 0; it < 4; it++) {
        int c = t + it * 256;
        int row = c >> 4, ch = c & 15;
        v8s val = {0, 0, 0, 0, 0, 0, 0, 0};
        if (m0 + row < N_NODES)
            val = *(const v8s*)&A[(size_t)(m0 + row) * 128 + ch * 8];
        *(v8s*)&As[row * 136 + ch * 8] = val;
    }
    __syncthreads();

    v4f acc[4][2] = {};
#pragma unroll
    for (int kt = 0; kt < 4; kt++)
#pragma unroll
        for (int mt = 0; mt < 4; mt++) {
            v8s a = *(const v8s*)&As[(mt * 16 + l15) * 136 + kt * 32 + q * 8];
            acc[mt][0] = MFMA(a, b[0][kt], acc[mt][0]);
            acc[mt][1] = MFMA(a, b[1][kt], acc[mt][1]);
        }
#pragma unroll
    for (int mt = 0; mt < 4; mt++)
#pragma unroll
        for (int r = 0; r < 4; r++) {
            int node = m0 + mt * 16 + q * 4 + r;
            if (node < N_NODES)
                *(unsigned int*)&C[(size_t)node * 512 + c0] =
                    pack2(acc[mt][0][r], acc[mt][1][r]);
        }

    float ps0 = asrc[c0], ps1 = asrc[c1];
    float pd0 = adst[c0], pd1 = adst[c1];
#pragma unroll
    for (int mt = 0; mt < 4; mt++)
#pragma unroll
        for (int r = 0; r < 4; r++) {
            float vs = acc[mt][0][r] * ps0 + acc[mt][1][r] * ps1;
            float vd = acc[mt][0][r] * pd0 + acc[mt][1][r] * pd1;
#pragma unroll
            for (int off = 1; off < 16; off <<= 1) {
                vs += __shfl_xor(vs, off);
                vd += __shfl_xor(vd, off);
            }
            if (l15 == 0) {
                alp[mt * 16 + q * 4 + r][w][0] = vs;
                alp[mt * 16 + q * 4 + r][w][1] = vd;
            }
        }
    __syncthreads();
    if (t < 64) {
        int node = m0 + t;
        if (node < N_NODES) {
            float ss = alp[t][0][0] + alp[t][1][0] + alp[t][2][0] + alp[t][3][0];
            float sd = alp[t][0][1] + alp[t][1][1] + alp[t][2][1] + alp[t][3][1];
            al_s[node * 4 + head] = ss;
            al_d[node * 4 + head] = sd;
        }
    }
}

// ------------------------------------------------------------ aggregation
// wave per node, single-pass softmax; branch-free prefetch of next edge.
__global__ __launch_bounds__(256) void k_aggregate(
        const unsigned short* __restrict__ xh, const float* __restrict__ al_src,
        const float* __restrict__ al_dst,
        const int* __restrict__ row_start, const int* __restrict__ csr_src,
        const float* __restrict__ bias,
        const float* __restrict__ bn_g, const float* __restrict__ bn_b,
        const float* __restrict__ bn_m, const float* __restrict__ bn_v,
        unsigned short* __restrict__ h, int relu_flag) {
    int w = threadIdx.x >> 6, l = threadIdx.x & 63;
    int n = blockIdx.x * 4 + w;
    int hh = l >> 4, c8 = l & 15;
    int r0 = row_start[n], r1 = row_start[n + 1];
    float ad = al_dst[n * 4 + hh];
    float sh = 0.f;
    float acc[8] = {};
    int scur = csr_src[r0];                        // deg >= 1 (self loop)
    float acur = al_src[scur * 4 + hh];
    v8s rcur = *(const v8s*)&xh[(size_t)scur * 512 + l * 8];
    for (int j = r0; j < r1; j++) {
        int jn = (j + 1 < r1) ? j + 1 : j;
        int snx = csr_src[jn];
        float anx = al_src[snx * 4 + hh];
        v8s rnx = *(const v8s*)&xh[(size_t)snx * 512 + l * 8];
        float a = acur + ad;
        a = (a >= 0.f) ? a : NEG * a;
        float we = __expf(a);
        sh += we;
#pragma unroll
        for (int i = 0; i < 8; i++)
            acc[i] = fmaf(we, b2f((unsigned short)rcur[i]), acc[i]);
        scur = snx; acur = anx; rcur = rnx;
    }
    float inv = 1.f / (sh + 1e-16f);
#pragma unroll
    for (int i = 0; i < 8; i++) {
        acc[i] *= inv;
        acc[i] += __shfl_xor(acc[i], 16);
        acc[i] += __shfl_xor(acc[i], 32);
    }
    if (hh == 0) {
        int cbase = c8 * 8;
        short o[8];
#pragma unroll
        for (int i = 0; i < 8; i++) {
            int c = cbase + i;
            float v = 0.25f * acc[i] + bias[c];
            v = (v - bn_m[c]) * rsqrtf(bn_v[c] + LN_EPS) * bn_g[c] + bn_b[c];
            if (relu_flag) v = fmaxf(v, 0.f);
            o[i] = (short)f2b(v);
        }
        *(v8s*)&h[(size_t)n * 128 + cbase] = *(const v8s*)o;
    }
}

// ------------------------------------------------------------ UV GEMM
__global__ __launch_bounds__(256, 4) void k_uvgemm(
        const unsigned short* __restrict__ A, const unsigned short* __restrict__ Wt,
        unsigned short* __restrict__ UV) {
    __shared__ __align__(16) unsigned short As[64 * 136];
    int t = threadIdx.x;
    int lane = t & 63, w = t >> 6, l15 = lane & 15, q = lane >> 4;
    int m0 = blockIdx.x * 64, n0 = blockIdx.y * 128;
    int c0 = n0 + w * 32 + 2 * l15;

    v8s b[2][4];
#pragma unroll
    for (int nt = 0; nt < 2; nt++)
#pragma unroll
        for (int kt = 0; kt < 4; kt++)
            b[nt][kt] = *(const v8s*)&Wt[(size_t)(c0 + nt) * 128 + kt * 32 + q * 8];
#pragma unroll
    for (int it = 0; it < 4; it++) {
        int c = t + it * 256;
        int row = c >> 4, ch = c & 15;
        v8s val = {0, 0, 0, 0, 0, 0, 0, 0};
        if (m0 + row < N_NODES)
            val = *(const v8s*)&A[(size_t)(m0 + row) * 128 + ch * 8];
        *(v8s*)&As[row * 136 + ch * 8] = val;
    }
    __syncthreads();

    v4f acc[4][2] = {};
#pragma unroll
    for (int kt = 0; kt < 4; kt++)
#pragma unroll
        for (int mt = 0; mt < 4; mt++) {
            v8s a = *(const v8s*)&As[(mt * 16 + l15) * 136 + kt * 32 + q * 8];
            acc[mt][0] = MFMA(a, b[0][kt], acc[mt][0]);
            acc[mt][1] = MFMA(a, b[1][kt], acc[mt][1]);
        }
#pragma unroll
    for (int mt = 0; mt < 4; mt++)
#pragma unroll
        for (int r = 0; r < 4; r++) {
            int node = m0 + mt * 16 + q * 4 + r;
            if (node < N_NODES)
                *(unsigned int*)&UV[(size_t)node * 256 + c0] =
                    pack2(acc[mt][0][r], acc[mt][1][r]);
        }
}

// ------------------------------------------------------------ edge MLP v3
// 16 lanes per edge (4 parallel edges per wave, 4 iterations). Lane owns 8
// channels: one v8s U load + one v8s V load; LN = 8 reg adds + 4 shfl steps.
__global__ __launch_bounds__(256) void k_edgemlp3(
        const unsigned short* __restrict__ UV, const int* __restrict__ ei,
        const void* __restrict__ eraw, const int* __restrict__ flag,
        const unsigned short* __restrict__ w1et, const float* __restrict__ em1b,
        const float* __restrict__ lng, const float* __restrict__ lnb,
        const unsigned short* __restrict__ w2t, const float* __restrict__ em2b,
        const float* __restrict__ em3w, const float* __restrict__ em3b,
        float* __restrict__ out) {
    __shared__ __align__(16) unsigned short za[64 * 136];   // 17408 B
    __shared__ __align__(16) unsigned short ea_s[64 * 8];
    __shared__ int idx_s[128];
    __shared__ float part[4][64];

    int t = threadIdx.x;
    int lane = t & 63, w = t >> 6, l15 = lane & 15, q = lane >> 4;
    int e0 = blockIdx.x * 64;
    int bf = flag[0];
    int cb = l15 * 8;    // this lane's 8 channels

    // per-lane constants
    v8s wreg[8];
#pragma unroll
    for (int j = 0; j < 8; j++)
        wreg[j] = *(const v8s*)&w1et[(cb + j) * 8];
    float bc[8], lg[8], lb[8];
#pragma unroll
    for (int j = 0; j < 8; j++) {
        bc[j] = em1b[cb + j];
        lg[j] = lng[cb + j];
        lb[j] = lnb[cb + j];
    }

    if (t < 64) {
        idx_s[t * 2]     = ei[e0 + t];
        idx_s[t * 2 + 1] = ei[N_EDGES + e0 + t];
        if (bf) {
            *(v8s*)&ea_s[t * 8] =
                *(const v8s*)((const unsigned short*)eraw + (size_t)(e0 + t) * 8);
        } else {
            short tmp[8];
#pragma unroll
            for (int j = 0; j < 8; j++)
                tmp[j] = (short)f2b(((const float*)eraw)[(size_t)(e0 + t) * 8 + j]);
            *(v8s*)&ea_s[t * 8] = *(const v8s*)tmp;
        }
    }
    __syncthreads();

#pragma unroll 1
    for (int i = 0; i < 4; i++) {
        int el = w * 16 + i * 4 + q;
        int src = idx_s[el * 2], dst = idx_s[el * 2 + 1];
        v8s uu = *(const v8s*)&UV[(size_t)src * 256 + cb];
        v8s vv = *(const v8s*)&UV[(size_t)dst * 256 + 128 + cb];
        v8s ea8 = *(const v8s*)&ea_s[el * 8];
        float eaf[8];
#pragma unroll
        for (int k = 0; k < 8; k++) eaf[k] = b2f((unsigned short)ea8[k]);
        float z[8];
        float s = 0.f, qq = 0.f;
#pragma unroll
        for (int j = 0; j < 8; j++) {
            float e = 0.f;
#pragma unroll
            for (int k = 0; k < 8; k++)
                e = fmaf(eaf[k], b2f((unsigned short)wreg[j][k]), e);
            float zz = b2f((unsigned short)uu[j]) + b2f((unsigned short)vv[j])
                     + e + bc[j];
            z[j] = zz;
            s += zz;
            qq = fmaf(zz, zz, qq);
        }
#pragma unroll
        for (int off = 1; off < 16; off <<= 1) {
            s  += __shfl_xor(s, off);
            qq += __shfl_xor(qq, off);
        }
        float mu = s * (1.f / 128.f);
        float var = qq * (1.f / 128.f) - mu * mu;
        float rstd = rsqrtf(var + LN_EPS);
        short o[8];
#pragma unroll
        for (int j = 0; j < 8; j++)
            o[j] = (short)f2b(fmaxf((z[j] - mu) * rstd * lg[j] + lb[j], 0.f));
        *(v8s*)&za[el * 136 + cb] = *(const v8s*)o;
    }
    __syncthreads();

    // layer 2 MFMA: wave w -> cols w*16..+15
    v8s b2[4];
#pragma unroll
    for (int kt = 0; kt < 4; kt++)
        b2[kt] = *(const v8s*)&w2t[(size_t)(w * 16 + l15) * 128 + kt * 32 + q * 8];
    v4f acc2[4] = {};
#pragma unroll
    for (int kt = 0; kt < 4; kt++)
#pragma unroll
        for (int mt = 0; mt < 4; mt++) {
            v8s a = *(const v8s*)&za[(mt * 16 + l15) * 136 + kt * 32 + q * 8];
            acc2[mt] = MFMA(a, b2[kt], acc2[mt]);
        }

    {
        int col = w * 16 + l15;
        float b2c = em2b[col], w3c = em3w[col];
#pragma unroll
        for (int mt = 0; mt < 4; mt++)
#pragma unroll
            for (int r = 0; r < 4; r++) {
                float vv = fmaxf(acc2[mt][r] + b2c, 0.f) * w3c;
#pragma unroll
                for (int off = 1; off < 16; off <<= 1) vv += __shfl_xor(vv, off);
                if (l15 == 0) part[w][mt * 16 + q * 4 + r] = vv;
            }
    }
    __syncthreads();
    if (t < 64)
        out[e0 + t] = part[0][t] + part[1][t] + part[2][t] + part[3][t]
                    + em3b[0];
}

// ------------------------------------------------------------ launch
extern "C" __attribute__((visibility("default")))
void kernel_launch(void* const* d_in, const int* in_sizes, int n_in,
                   void* d_out, int out_size, void* d_ws, size_t ws_size,
                   hipStream_t stream) {
    float* out = (float*)d_out;

    static const int EXP_SIZES[24] = {
        800000, 400000, 1600000, 50000, 2304, 128, 128, 128,
        196608, 1536, 1536, 384, 384, 384, 384, 384,
        33792, 128, 128, 128, 8192, 64, 64, 1};
    bool ok = (n_in == 24) && (out_size == N_EDGES);
    if (ok) for (int i = 0; i < 24; i++) ok = ok && (in_sizes[i] == EXP_SIZES[i]);
    if (!ok) {
        k_fill<<<(out_size + 255) / 256, 256, 0, stream>>>(out, out_size, 4.0f);
        return;
    }
    if (ws_size < (size_t)68000000) {
        k_fill<<<(out_size + 255) / 256, 256, 0, stream>>>(out, out_size, 8.0f);
        return;
    }

    const int* ei    = (const int*)d_in[1];
    const int* shock = (const int*)d_in[3];

    char* ws = (char*)d_ws;
    unsigned short* h_bf  = (unsigned short*)(ws + 0);          // 12,800,000
    unsigned short* xh    = (unsigned short*)(ws + 12800000);   // 51,200,000
    unsigned short* UV    = xh;   // aliases xh (xh dead before k_uvgemm)
    float* al_s    = (float*)(ws + 64000000);
    float* al_d    = (float*)(ws + 64800000);
    float* down    = (float*)(ws + 65600000);
    int*   deg     = (int*)  (ws + 65800000);
    int*   row_st  = (int*)  (ws + 66000000);
    int*   fill    = (int*)  (ws + 66200064);
    int*   csr_src = (int*)  (ws + 66400064);
    int*   flag    = (int*)  (ws + 67400064);
    unsigned short* gwt  = (unsigned short*)(ws + 67400128);    // 393,216
    unsigned short* uvt  = (unsigned short*)(ws + 67793344);    // 65,536
    unsigned short* w2t  = (unsigned short*)(ws + 67858880);    // 16,384
    unsigned short* w1et = (unsigned short*)(ws + 67875264);    // 2,048
    float* pool    = (float*)(ws + 67877312);                   // 8,200 f32
    int*   bsum    = (int*)  (ws + 67910112);                   // 784 B

    float* cencw = pool + 0;    float* cencb = pool + 2304;
    float* cenlg = pool + 2432; float* cenlb = pool + 2560;
    float* casrc = pool + 2688; float* cadst = pool + 4224;
    float* cbias = pool + 5760; float* cbng  = pool + 6144;
    float* cbnb  = pool + 6528; float* cbnm  = pool + 6912;
    float* cbnv  = pool + 7296; float* cem1b = pool + 7680;
    float* cemlg = pool + 7808; float* cemlb = pool + 7936;
    float* cem2b = pool + 8064; float* cem3w = pool + 8128;
    float* cem3b = pool + 8192;

    k_detect<<<1, 64, 0, stream>>>((const unsigned short*)d_in[0], flag);

    PrepArgs pa;
    pa.encw = d_in[4];  pa.encb = d_in[5];  pa.enlg = d_in[6];  pa.enlb = d_in[7];
    pa.gatw = d_in[8];  pa.asrc = d_in[9];  pa.adst = d_in[10]; pa.bias = d_in[11];
    pa.bng  = d_in[12]; pa.bnb  = d_in[13]; pa.bnm  = d_in[14]; pa.bnv  = d_in[15];
    pa.em1w = d_in[16]; pa.em1b = d_in[17]; pa.emlg = d_in[18]; pa.emlb = d_in[19];
    pa.em2w = d_in[20]; pa.em2b = d_in[21]; pa.em3w = d_in[22]; pa.em3b = d_in[23];
    k_prep<<<(PREP_ITEMS + 255) / 256, 256, 0, stream>>>(
        pa, pool, gwt, uvt, w2t, w1et, down, deg, fill, flag);

    k_graph<<<(ETOT + 255) / 256, 256, 0, stream>>>(ei, shock, down, deg);
    k_scan1<<<NSB, 256, 0, stream>>>(deg, bsum);
    k_scan2<<<NSB, 256, 0, stream>>>(deg, bsum, row_st);
    k_csr<<<(ETOT + 255) / 256, 256, 0, stream>>>(ei, row_st, fill, csr_src);
    k_encoder<<<N_NODES / 4, 256, 0, stream>>>(
        d_in[0], flag, shock, down, cencw, cencb, cenlg, cenlb, h_bf);
    for (int i = 0; i < 3; i++) {
        k_gemm<<<dim3(782, 4), 256, 0, stream>>>(
            h_bf, gwt + (size_t)i * 65536, casrc + i * 512, cadst + i * 512,
            xh, al_s, al_d);
        k_aggregate<<<N_NODES / 4, 256, 0, stream>>>(
            xh, al_s, al_d, row_st, csr_src,
            cbias + i * 128, cbng + i * 128, cbnb + i * 128,
            cbnm + i * 128, cbnv + i * 128, h_bf, (i < 2) ? 1 : 0);
    }
    k_uvgemm<<<dim3(782, 2), 256, 0, stream>>>(h_bf, uvt, UV);
    k_edgemlp3<<<N_EDGES / 64, 256, 0, stream>>>(
        UV, ei, d_in[2], flag, w1et, cem1b, cemlg, cemlb,
        w2t, cem2b, cem3w, cem3b, out);
}

// Round 14
// 462.081 us; speedup vs baseline: 1.7492x; 1.0106x over previous
//
#include <hip/hip_runtime.h>
#include <hip/hip_bf16.h>

// ShockPropagationGNN — round 13 (base: round 12, 467us).
// - edgemlp3: ea@W1e back to fp32 LDS (accuracy 0.027->~0.01; frees 32 VGPRs
//   of bf16 wreg -> occupancy up), float4 LDS reads.
// - aggregate: depth-2 csr index prefetch (break index->data load chain).

#define N_NODES 50000
#define N_EDGES 200000
#define ETOT    (N_EDGES + N_NODES)
#define HID     128
#define LN_EPS  1e-5f
#define NEG     0.2f
#define NSB     196

typedef __hip_bfloat16 bf16;
typedef __attribute__((ext_vector_type(8))) short v8s;
typedef __attribute__((ext_vector_type(4))) float v4f;
#define MFMA(a, b, c) __builtin_amdgcn_mfma_f32_16x16x32_bf16(a, b, c, 0, 0, 0)

__device__ __forceinline__ float b2f(unsigned short s) {
    return __uint_as_float(((unsigned int)s) << 16);
}
__device__ __forceinline__ unsigned short f2b(float f) {
    __hip_bfloat16 h = __float2bfloat16(f);
    return *reinterpret_cast<unsigned short*>(&h);
}
__device__ __forceinline__ unsigned int pack2(float a, float b) {
    return (unsigned int)f2b(a) | ((unsigned int)f2b(b) << 16);
}
__device__ __forceinline__ float pread(const void* p, size_t i, int isbf) {
    if (isbf) return b2f(((const unsigned short*)p)[i]);
    return ((const float*)p)[i];
}

__global__ void k_fill(float* out, int n, float v) {
    int i = blockIdx.x * blockDim.x + threadIdx.x;
    if (i < n) out[i] = v;
}

// ------------------------------------------------------------ dtype detect
__global__ void k_detect(const unsigned short* __restrict__ xbuf,
                         int* __restrict__ flag) {
    int sane = 0;
    for (int j = threadIdx.x; j < 4096; j += 64) {
        unsigned short v = xbuf[2 * j];
        int e = (v >> 7) & 0xFF;
        if (v == 0 || (e > 96 && e < 160)) sane++;
    }
    for (int off = 32; off > 0; off >>= 1) sane += __shfl_down(sane, off);
    if (threadIdx.x == 0) flag[0] = (sane * 10 >= 4096 * 9) ? 1 : 0;
}

// ------------------------------------------------------------ prep (fused)
struct PrepArgs {
    const void *encw, *encb, *enlg, *enlb, *gatw, *asrc, *adst, *bias,
               *bng, *bnb, *bnm, *bnv, *em1w, *em1b, *emlg, *emlb,
               *em2w, *em2b, *em3w, *em3b;
};
// zeros | pool | w1e(fp32) | gwt | uvt | w2t
#define PREP_ITEMS (150000 + 8193 + 1024 + 196608 + 32768 + 8192)
__global__ void k_prep(PrepArgs a, float* __restrict__ pool,
                       unsigned short* __restrict__ gwt,   // [L][n=512][k=128]
                       unsigned short* __restrict__ uvt,   // [n=256][k=128]
                       unsigned short* __restrict__ w2t,   // [n=64][k=128]
                       float* __restrict__ down, int* __restrict__ deg,
                       int* __restrict__ fill, const int* __restrict__ flag) {
    int i = blockIdx.x * 256 + threadIdx.x;
    int bf = flag[0];
    if (i < 150000) {
        int which = i / 50000, idx = i - which * 50000;
        if (which == 0) down[idx] = 0.f;
        else if (which == 1) deg[idx] = 0;
        else fill[idx] = 0;
        return;
    }
    i -= 150000;
    if (i < 8193) {
        const void* s; int off;
        if      (i < 2304) { s = a.encw; off = 0;    }
        else if (i < 2432) { s = a.encb; off = 2304; }
        else if (i < 2560) { s = a.enlg; off = 2432; }
        else if (i < 2688) { s = a.enlb; off = 2560; }
        else if (i < 4224) { s = a.asrc; off = 2688; }
        else if (i < 5760) { s = a.adst; off = 4224; }
        else if (i < 6144) { s = a.bias; off = 5760; }
        else if (i < 6528) { s = a.bng;  off = 6144; }
        else if (i < 6912) { s = a.bnb;  off = 6528; }
        else if (i < 7296) { s = a.bnm;  off = 6912; }
        else if (i < 7680) { s = a.bnv;  off = 7296; }
        else if (i < 7808) { s = a.em1b; off = 7680; }
        else if (i < 7936) { s = a.emlg; off = 7808; }
        else if (i < 8064) { s = a.emlb; off = 7936; }
        else if (i < 8128) { s = a.em2b; off = 8064; }
        else if (i < 8192) { s = a.em3w; off = 8128; }
        else               { s = a.em3b; off = 8192; }
        pool[i] = pread(s, i - off, bf);
        return;
    }
    i -= 8193;
    if (i < 1024) {     // w1e fp32: pool[8200 + k*128+c] = em1_w[256+k][c]
        int k = i >> 7, c = i & 127;
        pool[8200 + i] = pread(a.em1w, (size_t)(256 + k) * 128 + c, bf);
        return;
    }
    i -= 1024;
    if (i < 196608) {   // gwt[L][n][k] = gat_w[L][k][n]
        int L = i >> 16, rem = i & 65535, n = rem >> 7, k = rem & 127;
        gwt[i] = f2b(pread(a.gatw, (size_t)L * 65536 + (size_t)k * 512 + n, bf));
        return;
    }
    i -= 196608;
    if (i < 32768) {    // uvt[n][k]: n<128 -> em1_w[k][n]; else em1_w[128+k][n-128]
        int n = i >> 7, k = i & 127;
        float v = (n < 128) ? pread(a.em1w, (size_t)k * 128 + n, bf)
                            : pread(a.em1w, (size_t)(128 + k) * 128 + (n - 128), bf);
        uvt[i] = f2b(v);
        return;
    }
    i -= 32768;
    if (i < 8192) {     // w2t[n][k] = em2_w[k][n]
        int n = i >> 7, k = i & 127;
        w2t[i] = f2b(pread(a.em2w, (size_t)k * 64 + n, bf));
    }
}

// ------------------------------------------------------------ graph build
__global__ void k_graph(const int* __restrict__ ei, const int* __restrict__ shock,
                        float* __restrict__ down, int* __restrict__ deg) {
    int e = blockIdx.x * blockDim.x + threadIdx.x;
    if (e < ETOT) {
        int d = (e < N_EDGES) ? ei[N_EDGES + e] : (e - N_EDGES);
        atomicAdd(&deg[d], 1);
        if (e < N_EDGES && shock[ei[e]] != 0) down[d] = 1.f;
    }
}

// ------------------------------------------------------------ scan (2-phase)
__global__ __launch_bounds__(256) void k_scan1(
        const int* __restrict__ deg, int* __restrict__ bsum) {
    __shared__ int red[4];
    int b = blockIdx.x, t = threadIdx.x, lane = t & 63, w = t >> 6;
    int idx = b * 256 + t;
    int v = (idx < N_NODES) ? deg[idx] : 0;
#pragma unroll
    for (int off = 1; off < 64; off <<= 1) v += __shfl_xor(v, off);
    if (lane == 0) red[w] = v;
    __syncthreads();
    if (t == 0) bsum[b] = red[0] + red[1] + red[2] + red[3];
}

__global__ __launch_bounds__(256) void k_scan2(
        const int* __restrict__ deg, const int* __restrict__ bsum,
        int* __restrict__ row_start) {
    __shared__ int red[4];
    __shared__ int wsum[4];
    int b = blockIdx.x, t = threadIdx.x, lane = t & 63, w = t >> 6;
    int pv = (t < b) ? bsum[t] : 0;
    int sm = pv;
#pragma unroll
    for (int off = 1; off < 64; off <<= 1) sm += __shfl_xor(sm, off);
    if (lane == 0) red[w] = sm;
    int idx = b * 256 + t;
    int v = (idx < N_NODES) ? deg[idx] : 0;
    int inc = v;
#pragma unroll
    for (int off = 1; off < 64; off <<= 1) {
        int u = __shfl_up(inc, off);
        if (lane >= off) inc += u;
    }
    if (lane == 63) wsum[w] = inc;
    __syncthreads();
    int boff = red[0] + red[1] + red[2] + red[3];
    int wo = 0;
#pragma unroll
    for (int i = 0; i < 4; i++) if (i < w) wo += wsum[i];
    if (idx < N_NODES) row_start[idx] = boff + wo + (inc - v);
    if (b == 0 && t == 0) row_start[N_NODES] = ETOT;
}

__global__ void k_csr(const int* __restrict__ ei, const int* __restrict__ row_start,
                      int* __restrict__ fill, int* __restrict__ csr_src) {
    int e = blockIdx.x * blockDim.x + threadIdx.x;
    if (e < ETOT) {
        int s, d;
        if (e < N_EDGES) { s = ei[e]; d = ei[N_EDGES + e]; }
        else             { s = e - N_EDGES; d = s; }
        int pos = row_start[d] + atomicAdd(&fill[d], 1);
        csr_src[pos] = s;
    }
}

// ------------------------------------------------------------ encoder -> h bf16
__global__ __launch_bounds__(256) void k_encoder(
        const void* __restrict__ xraw, const int* __restrict__ flag,
        const int* __restrict__ shock, const float* __restrict__ down,
        const float* __restrict__ enc_w, const float* __restrict__ enc_b,
        const float* __restrict__ ln_g, const float* __restrict__ ln_b,
        unsigned short* __restrict__ h) {
    __shared__ float sw[2304];
    __shared__ float sp[384];
    int t = threadIdx.x;
    for (int i = t; i < 2304; i += 256) sw[i] = enc_w[i];
    if (t < 128)      sp[t] = enc_b[t];
    else if (t < 256) sp[t] = ln_g[t - 128];
    if (t < 128)      sp[256 + t] = ln_b[t];
    __syncthreads();

    int w = t >> 6, l = t & 63;
    int n = blockIdx.x * 4 + w;
    int bf = flag[0];
    int c0 = 2 * l, c1 = c0 + 1;

    float xv = (l < 16) ? pread(xraw, (size_t)n * 16 + l, bf) : 0.f;
    float xs = (float)shock[n];
    float xd = down[n];

    float a0 = sp[c0], a1 = sp[c1];
#pragma unroll
    for (int k = 0; k < 16; k++) {
        float xk = __shfl(xv, k);
        a0 = fmaf(xk, sw[k * HID + c0], a0);
        a1 = fmaf(xk, sw[k * HID + c1], a1);
    }
    a0 = fmaf(xs, sw[16 * HID + c0], a0); a1 = fmaf(xs, sw[16 * HID + c1], a1);
    a0 = fmaf(xd, sw[17 * HID + c0], a0); a1 = fmaf(xd, sw[17 * HID + c1], a1);

    float s = a0 + a1, q = a0 * a0 + a1 * a1;
#pragma unroll
    for (int off = 1; off < 64; off <<= 1) {
        s += __shfl_xor(s, off);
        q += __shfl_xor(q, off);
    }
    float mu = s * (1.f / 128.f);
    float var = q * (1.f / 128.f) - mu * mu;
    float rstd = rsqrtf(var + LN_EPS);
    float v0 = fmaxf((a0 - mu) * rstd * sp[128 + c0] + sp[256 + c0], 0.f);
    float v1 = fmaxf((a1 - mu) * rstd * sp[128 + c1] + sp[256 + c1], 0.f);
    *(unsigned int*)&h[(size_t)n * HID + c0] = pack2(v0, v1);
}

// ------------------------------------------------------------ GAT GEMM + logits
__global__ __launch_bounds__(256, 4) void k_gemm(
        const unsigned short* __restrict__ A, const unsigned short* __restrict__ Wt,
        const float* __restrict__ asrc, const float* __restrict__ adst,
        unsigned short* __restrict__ C,
        float* __restrict__ al_s, float* __restrict__ al_d) {
    __shared__ __align__(16) unsigned short As[64 * 136];
    __shared__ float alp[64][4][2];
    int t = threadIdx.x;
    int lane = t & 63, w = t >> 6, l15 = lane & 15, q = lane >> 4;
    int m0 = blockIdx.x * 64, n0 = blockIdx.y * 128, head = blockIdx.y;
    int c0 = n0 + w * 32 + 2 * l15, c1 = c0 + 1;

    v8s b[2][4];
#pragma unroll
    for (int nt = 0; nt < 2; nt++)
#pragma unroll
        for (int kt = 0; kt < 4; kt++)
            b[nt][kt] = *(const v8s*)&Wt[(size_t)(c0 + nt) * 128 + kt * 32 + q * 8];
#pragma unroll
    for (int it = 0; it < 4; it++) {
        int c = t + it * 256;
        int row = c >> 4, ch = c & 15;
        v8s val = {0, 0, 0, 0, 0, 0, 0, 0};
        if (m0 + row < N_NODES)
            val = *(const v8s*)&A[(size_t)(m0 + row) * 128 + ch * 8];
        *(v8s*)&As[row * 136 + ch * 8] = val;
    }
    __syncthreads();

    v4f acc[4][2] = {};
#pragma unroll
    for (int kt = 0; kt < 4; kt++)
#pragma unroll
        for (int mt = 0; mt < 4; mt++) {
            v8s a = *(const v8s*)&As[(mt * 16 + l15) * 136 + kt * 32 + q * 8];
            acc[mt][0] = MFMA(a, b[0][kt], acc[mt][0]);
            acc[mt][1] = MFMA(a, b[1][kt], acc[mt][1]);
        }
#pragma unroll
    for (int mt = 0; mt < 4; mt++)
#pragma unroll
        for (int r = 0; r < 4; r++) {
            int node = m0 + mt * 16 + q * 4 + r;
            if (node < N_NODES)
                *(unsigned int*)&C[(size_t)node * 512 + c0] =
                    pack2(acc[mt][0][r], acc[mt][1][r]);
        }

    float ps0 = asrc[c0], ps1 = asrc[c1];
    float pd0 = adst[c0], pd1 = adst[c1];
#pragma unroll
    for (int mt = 0; mt < 4; mt++)
#pragma unroll
        for (int r = 0; r < 4; r++) {
            float vs = acc[mt][0][r] * ps0 + acc[mt][1][r] * ps1;
            float vd = acc[mt][0][r] * pd0 + acc[mt][1][r] * pd1;
#pragma unroll
            for (int off = 1; off < 16; off <<= 1) {
                vs += __shfl_xor(vs, off);
                vd += __shfl_xor(vd, off);
            }
            if (l15 == 0) {
                alp[mt * 16 + q * 4 + r][w][0] = vs;
                alp[mt * 16 + q * 4 + r][w][1] = vd;
            }
        }
    __syncthreads();
    if (t < 64) {
        int node = m0 + t;
        if (node < N_NODES) {
            float ss = alp[t][0][0] + alp[t][1][0] + alp[t][2][0] + alp[t][3][0];
            float sd = alp[t][0][1] + alp[t][1][1] + alp[t][2][1] + alp[t][3][1];
            al_s[node * 4 + head] = ss;
            al_d[node * 4 + head] = sd;
        }
    }
}

// ------------------------------------------------------------ aggregation
// wave per node, single-pass softmax; depth-2 index / depth-1 data prefetch.
__global__ __launch_bounds__(256) void k_aggregate(
        const unsigned short* __restrict__ xh, const float* __restrict__ al_src,
        const float* __restrict__ al_dst,
        const int* __restrict__ row_start, const int* __restrict__ csr_src,
        const float* __restrict__ bias,
        const float* __restrict__ bn_g, const float* __restrict__ bn_b,
        const float* __restrict__ bn_m, const float* __restrict__ bn_v,
        unsigned short* __restrict__ h, int relu_flag) {
    int w = threadIdx.x >> 6, l = threadIdx.x & 63;
    int n = blockIdx.x * 4 + w;
    int hh = l >> 4, c8 = l & 15;
    int r0 = row_start[n], r1 = row_start[n + 1];
    float ad = al_dst[n * 4 + hh];
    float sh = 0.f;
    float acc[8] = {};
    int last = r1 - 1;
    int i0 = csr_src[r0];                          // deg >= 1 (self loop)
    int i1 = csr_src[(r0 + 1 < r1) ? r0 + 1 : last];
    float aC = al_src[i0 * 4 + hh];
    v8s rC = *(const v8s*)&xh[(size_t)i0 * 512 + l * 8];
    for (int j = r0; j < r1; j++) {
        int i2 = csr_src[(j + 2 < r1) ? j + 2 : last];
        float aN = al_src[i1 * 4 + hh];
        v8s rN = *(const v8s*)&xh[(size_t)i1 * 512 + l * 8];
        float a = aC + ad;
        a = (a >= 0.f) ? a : NEG * a;
        float we = __expf(a);
        sh += we;
#pragma unroll
        for (int i = 0; i < 8; i++)
            acc[i] = fmaf(we, b2f((unsigned short)rC[i]), acc[i]);
        aC = aN; rC = rN; i1 = i2;
    }
    float inv = 1.f / (sh + 1e-16f);
#pragma unroll
    for (int i = 0; i < 8; i++) {
        acc[i] *= inv;
        acc[i] += __shfl_xor(acc[i], 16);
        acc[i] += __shfl_xor(acc[i], 32);
    }
    if (hh == 0) {
        int cbase = c8 * 8;
        short o[8];
#pragma unroll
        for (int i = 0; i < 8; i++) {
            int c = cbase + i;
            float v = 0.25f * acc[i] + bias[c];
            v = (v - bn_m[c]) * rsqrtf(bn_v[c] + LN_EPS) * bn_g[c] + bn_b[c];
            if (relu_flag) v = fmaxf(v, 0.f);
            o[i] = (short)f2b(v);
        }
        *(v8s*)&h[(size_t)n * 128 + cbase] = *(const v8s*)o;
    }
}

// ------------------------------------------------------------ UV GEMM
__global__ __launch_bounds__(256, 4) void k_uvgemm(
        const unsigned short* __restrict__ A, const unsigned short* __restrict__ Wt,
        unsigned short* __restrict__ UV) {
    __shared__ __align__(16) unsigned short As[64 * 136];
    int t = threadIdx.x;
    int lane = t & 63, w = t >> 6, l15 = lane & 15, q = lane >> 4;
    int m0 = blockIdx.x * 64, n0 = blockIdx.y * 128;
    int c0 = n0 + w * 32 + 2 * l15;

    v8s b[2][4];
#pragma unroll
    for (int nt = 0; nt < 2; nt++)
#pragma unroll
        for (int kt = 0; kt < 4; kt++)
            b[nt][kt] = *(const v8s*)&Wt[(size_t)(c0 + nt) * 128 + kt * 32 + q * 8];
#pragma unroll
    for (int it = 0; it < 4; it++) {
        int c = t + it * 256;
        int row = c >> 4, ch = c & 15;
        v8s val = {0, 0, 0, 0, 0, 0, 0, 0};
        if (m0 + row < N_NODES)
            val = *(const v8s*)&A[(size_t)(m0 + row) * 128 + ch * 8];
        *(v8s*)&As[row * 136 + ch * 8] = val;
    }
    __syncthreads();

    v4f acc[4][2] = {};
#pragma unroll
    for (int kt = 0; kt < 4; kt++)
#pragma unroll
        for (int mt = 0; mt < 4; mt++) {
            v8s a = *(const v8s*)&As[(mt * 16 + l15) * 136 + kt * 32 + q * 8];
            acc[mt][0] = MFMA(a, b[0][kt], acc[mt][0]);
            acc[mt][1] = MFMA(a, b[1][kt], acc[mt][1]);
        }
#pragma unroll
    for (int mt = 0; mt < 4; mt++)
#pragma unroll
        for (int r = 0; r < 4; r++) {
            int node = m0 + mt * 16 + q * 4 + r;
            if (node < N_NODES)
                *(unsigned int*)&UV[(size_t)node * 256 + c0] =
                    pack2(acc[mt][0][r], acc[mt][1][r]);
        }
}

// ------------------------------------------------------------ edge MLP v3b
// 16 lanes per edge (4 parallel edges/wave). ea@W1e from fp32 LDS (float4
// reads); LN = 8 reg adds + 4 shfl steps over 16 lanes.
__global__ __launch_bounds__(256) void k_edgemlp3(
        const unsigned short* __restrict__ UV, const int* __restrict__ ei,
        const void* __restrict__ eraw, const int* __restrict__ flag,
        const float* __restrict__ w1e, const float* __restrict__ em1b,
        const float* __restrict__ lng, const float* __restrict__ lnb,
        const unsigned short* __restrict__ w2t, const float* __restrict__ em2b,
        const float* __restrict__ em3w, const float* __restrict__ em3b,
        float* __restrict__ out) {
    __shared__ __align__(16) unsigned short za[64 * 136];   // 17408 B
    __shared__ __align__(16) float w1e_s[1024];             // 4096 B
    __shared__ __align__(16) unsigned short ea_s[64 * 8];
    __shared__ int idx_s[128];
    __shared__ float part[4][64];

    int t = threadIdx.x;
    int lane = t & 63, w = t >> 6, l15 = lane & 15, q = lane >> 4;
    int e0 = blockIdx.x * 64;
    int bf = flag[0];
    int cb = l15 * 8;    // this lane's 8 channels

    float bc[8], lg[8], lb[8];
#pragma unroll
    for (int j = 0; j < 8; j++) {
        bc[j] = em1b[cb + j];
        lg[j] = lng[cb + j];
        lb[j] = lnb[cb + j];
    }

    for (int i = t; i < 1024; i += 256) w1e_s[i] = w1e[i];
    if (t < 64) {
        idx_s[t * 2]     = ei[e0 + t];
        idx_s[t * 2 + 1] = ei[N_EDGES + e0 + t];
        if (bf) {
            *(v8s*)&ea_s[t * 8] =
                *(const v8s*)((const unsigned short*)eraw + (size_t)(e0 + t) * 8);
        } else {
            short tmp[8];
#pragma unroll
            for (int j = 0; j < 8; j++)
                tmp[j] = (short)f2b(((const float*)eraw)[(size_t)(e0 + t) * 8 + j]);
            *(v8s*)&ea_s[t * 8] = *(const v8s*)tmp;
        }
    }
    __syncthreads();

#pragma unroll 1
    for (int i = 0; i < 4; i++) {
        int el = w * 16 + i * 4 + q;
        int src = idx_s[el * 2], dst = idx_s[el * 2 + 1];
        v8s uu = *(const v8s*)&UV[(size_t)src * 256 + cb];
        v8s vv = *(const v8s*)&UV[(size_t)dst * 256 + 128 + cb];
        v8s ea8 = *(const v8s*)&ea_s[el * 8];
        float eaf[8];
#pragma unroll
        for (int k = 0; k < 8; k++) eaf[k] = b2f((unsigned short)ea8[k]);
        float e[8] = {};
#pragma unroll
        for (int k = 0; k < 8; k++) {
            float4 wa = *(const float4*)&w1e_s[k * 128 + cb];
            float4 wb = *(const float4*)&w1e_s[k * 128 + cb + 4];
            e[0] = fmaf(eaf[k], wa.x, e[0]);
            e[1] = fmaf(eaf[k], wa.y, e[1]);
            e[2] = fmaf(eaf[k], wa.z, e[2]);
            e[3] = fmaf(eaf[k], wa.w, e[3]);
            e[4] = fmaf(eaf[k], wb.x, e[4]);
            e[5] = fmaf(eaf[k], wb.y, e[5]);
            e[6] = fmaf(eaf[k], wb.z, e[6]);
            e[7] = fmaf(eaf[k], wb.w, e[7]);
        }
        float z[8];
        float s = 0.f, qq = 0.f;
#pragma unroll
        for (int j = 0; j < 8; j++) {
            float zz = b2f((unsigned short)uu[j]) + b2f((unsigned short)vv[j])
                     + e[j] + bc[j];
            z[j] = zz;
            s += zz;
            qq = fmaf(zz, zz, qq);
        }
#pragma unroll
        for (int off = 1; off < 16; off <<= 1) {
            s  += __shfl_xor(s, off);
            qq += __shfl_xor(qq, off);
        }
        float mu = s * (1.f / 128.f);
        float var = qq * (1.f / 128.f) - mu * mu;
        float rstd = rsqrtf(var + LN_EPS);
        short o[8];
#pragma unroll
        for (int j = 0; j < 8; j++)
            o[j] = (short)f2b(fmaxf((z[j] - mu) * rstd * lg[j] + lb[j], 0.f));
        *(v8s*)&za[el * 136 + cb] = *(const v8s*)o;
    }
    __syncthreads();

    // layer 2 MFMA: wave w -> cols w*16..+15
    v8s b2[4];
#pragma unroll
    for (int kt = 0; kt < 4; kt++)
        b2[kt] = *(const v8s*)&w2t[(size_t)(w * 16 + l15) * 128 + kt * 32 + q * 8];
    v4f acc2[4] = {};
#pragma unroll
    for (int kt = 0; kt < 4; kt++)
#pragma unroll
        for (int mt = 0; mt < 4; mt++) {
            v8s a = *(const v8s*)&za[(mt * 16 + l15) * 136 + kt * 32 + q * 8];
            acc2[mt] = MFMA(a, b2[kt], acc2[mt]);
        }

    {
        int col = w * 16 + l15;
        float b2c = em2b[col], w3c = em3w[col];
#pragma unroll
        for (int mt = 0; mt < 4; mt++)
#pragma unroll
            for (int r = 0; r < 4; r++) {
                float vv = fmaxf(acc2[mt][r] + b2c, 0.f) * w3c;
#pragma unroll
                for (int off = 1; off < 16; off <<= 1) vv += __shfl_xor(vv, off);
                if (l15 == 0) part[w][mt * 16 + q * 4 + r] = vv;
            }
    }
    __syncthreads();
    if (t < 64)
        out[e0 + t] = part[0][t] + part[1][t] + part[2][t] + part[3][t]
                    + em3b[0];
}

// ------------------------------------------------------------ launch
extern "C" __attribute__((visibility("default")))
void kernel_launch(void* const* d_in, const int* in_sizes, int n_in,
                   void* d_out, int out_size, void* d_ws, size_t ws_size,
                   hipStream_t stream) {
    float* out = (float*)d_out;

    static const int EXP_SIZES[24] = {
        800000, 400000, 1600000, 50000, 2304, 128, 128, 128,
        196608, 1536, 1536, 384, 384, 384, 384, 384,
        33792, 128, 128, 128, 8192, 64, 64, 1};
    bool ok = (n_in == 24) && (out_size == N_EDGES);
    if (ok) for (int i = 0; i < 24; i++) ok = ok && (in_sizes[i] == EXP_SIZES[i]);
    if (!ok) {
        k_fill<<<(out_size + 255) / 256, 256, 0, stream>>>(out, out_size, 4.0f);
        return;
    }
    if (ws_size < (size_t)68000000) {
        k_fill<<<(out_size + 255) / 256, 256, 0, stream>>>(out, out_size, 8.0f);
        return;
    }

    const int* ei    = (const int*)d_in[1];
    const int* shock = (const int*)d_in[3];

    char* ws = (char*)d_ws;
    unsigned short* h_bf  = (unsigned short*)(ws + 0);          // 12,800,000
    unsigned short* xh    = (unsigned short*)(ws + 12800000);   // 51,200,000
    unsigned short* UV    = xh;   // aliases xh (xh dead before k_uvgemm)
    float* al_s    = (float*)(ws + 64000000);
    float* al_d    = (float*)(ws + 64800000);
    float* down    = (float*)(ws + 65600000);
    int*   deg     = (int*)  (ws + 65800000);
    int*   row_st  = (int*)  (ws + 66000000);
    int*   fill    = (int*)  (ws + 66200064);
    int*   csr_src = (int*)  (ws + 66400064);
    int*   flag    = (int*)  (ws + 67400064);
    unsigned short* gwt = (unsigned short*)(ws + 67400128);     // 393,216
    unsigned short* uvt = (unsigned short*)(ws + 67793344);     // 65,536
    unsigned short* w2t = (unsigned short*)(ws + 67858880);     // 16,384
    float* pool    = (float*)(ws + 67875264);                   // 9,224 f32
    int*   bsum    = (int*)  (ws + 67912160);                   // 784 B

    float* cencw = pool + 0;    float* cencb = pool + 2304;
    float* cenlg = pool + 2432; float* cenlb = pool + 2560;
    float* casrc = pool + 2688; float* cadst = pool + 4224;
    float* cbias = pool + 5760; float* cbng  = pool + 6144;
    float* cbnb  = pool + 6528; float* cbnm  = pool + 6912;
    float* cbnv  = pool + 7296; float* cem1b = pool + 7680;
    float* cemlg = pool + 7808; float* cemlb = pool + 7936;
    float* cem2b = pool + 8064; float* cem3w = pool + 8128;
    float* cem3b = pool + 8192;
    float* w1e   = pool + 8200;   // [8][128] fp32

    k_detect<<<1, 64, 0, stream>>>((const unsigned short*)d_in[0], flag);

    PrepArgs pa;
    pa.encw = d_in[4];  pa.encb = d_in[5];  pa.enlg = d_in[6];  pa.enlb = d_in[7];
    pa.gatw = d_in[8];  pa.asrc = d_in[9];  pa.adst = d_in[10]; pa.bias = d_in[11];
    pa.bng  = d_in[12]; pa.bnb  = d_in[13]; pa.bnm  = d_in[14]; pa.bnv  = d_in[15];
    pa.em1w = d_in[16]; pa.em1b = d_in[17]; pa.emlg = d_in[18]; pa.emlb = d_in[19];
    pa.em2w = d_in[20]; pa.em2b = d_in[21]; pa.em3w = d_in[22]; pa.em3b = d_in[23];
    k_prep<<<(PREP_ITEMS + 255) / 256, 256, 0, stream>>>(
        pa, pool, gwt, uvt, w2t, down, deg, fill, flag);

    k_graph<<<(ETOT + 255) / 256, 256, 0, stream>>>(ei, shock, down, deg);
    k_scan1<<<NSB, 256, 0, stream>>>(deg, bsum);
    k_scan2<<<NSB, 256, 0, stream>>>(deg, bsum, row_st);
    k_csr<<<(ETOT + 255) / 256, 256, 0, stream>>>(ei, row_st, fill, csr_src);
    k_encoder<<<N_NODES / 4, 256, 0, stream>>>(
        d_in[0], flag, shock, down, cencw, cencb, cenlg, cenlb, h_bf);
    for (int i = 0; i < 3; i++) {
        k_gemm<<<dim3(782, 4), 256, 0, stream>>>(
            h_bf, gwt + (size_t)i * 65536, casrc + i * 512, cadst + i * 512,
            xh, al_s, al_d);
        k_aggregate<<<N_NODES / 4, 256, 0, stream>>>(
            xh, al_s, al_d, row_st, csr_src,
            cbias + i * 128, cbng + i * 128, cbnb + i * 128,
            cbnm + i * 128, cbnv + i * 128, h_bf, (i < 2) ? 1 : 0);
    }
    k_uvgemm<<<dim3(782, 2), 256, 0, stream>>>(h_bf, uvt, UV);
    k_edgemlp3<<<N_EDGES / 64, 256, 0, stream>>>(
        UV, ei, d_in[2], flag, w1e, cem1b, cemlg, cemlb,
        w2t, cem2b, cem3w, cem3b, out);
}